// Round 1
// baseline (267.147 us; speedup 1.0000x reference)
//
#include <hip/hip_runtime.h>
#include <hip/hip_bf16.h>

// Shapes: M=128, H=256, F=256, T=4, I=2, NSEM=57
#define M_ 128
#define H_ 256
#define F_ 256
#define T_ 4
#define NSEM_ 57

__device__ __forceinline__ float4 ld4(const float* p) { return *reinterpret_cast<const float4*>(p); }
__device__ __forceinline__ void st4(float* p, float4 v) { *reinterpret_cast<float4*>(p) = v; }
__device__ __forceinline__ float4 add4(float4 a, float4 b) { return make_float4(a.x+b.x, a.y+b.y, a.z+b.z, a.w+b.w); }
__device__ __forceinline__ float4 relu4(float4 a) { return make_float4(fmaxf(a.x,0.f), fmaxf(a.y,0.f), fmaxf(a.z,0.f), fmaxf(a.w,0.f)); }
__device__ __forceinline__ float4 max4(float4 a, float4 b) { return make_float4(fmaxf(a.x,b.x), fmaxf(a.y,b.y), fmaxf(a.z,b.z), fmaxf(a.w,b.w)); }
__device__ __forceinline__ float4 fma4(float s, float4 w, float4 c) { return make_float4(fmaf(s,w.x,c.x), fmaf(s,w.y,c.y), fmaf(s,w.z,c.z), fmaf(s,w.w,c.w)); }

// ---------------------------------------------------------------------------
// K1a: partial parent matmul. grid 256 (128 col-blocks x 2 k-chunks), 256 thr.
// part[kc*32768 + col] = sum_{k in chunk} pf[k] * Wp[k*32768 + col]
// ---------------------------------------------------------------------------
__global__ void __launch_bounds__(256) k_parent_partial(
    const float* __restrict__ pf, const float* __restrict__ Wp,
    float* __restrict__ part)
{
  const int col = (blockIdx.x & 127) * 256 + threadIdx.x;
  const int kc  = blockIdx.x >> 7;
  __shared__ float spf[128];
  if (threadIdx.x < 128) spf[threadIdx.x] = pf[kc * 128 + threadIdx.x];
  __syncthreads();
  const float* w = Wp + (size_t)kc * 128 * 32768 + col;
  float acc = 0.f;
  #pragma unroll 16
  for (int k = 0; k < 128; ++k)
    acc = fmaf(spf[k], w[(size_t)k * 32768], acc);
  part[kc * 32768 + col] = acc;
}

// K1b: combine partials + bias + relu -> cf0. grid 128 x 256.
__global__ void __launch_bounds__(256) k_parent_combine(
    const float* __restrict__ part, const float* __restrict__ bp,
    float* __restrict__ cf0)
{
  const int col = blockIdx.x * 256 + threadIdx.x;
  float v = part[col] + part[32768 + col] + bp[col];
  cf0[col] = fmaxf(v, 0.f);
}

// ---------------------------------------------------------------------------
// K2: A = cf0 @ Wel[:H], B = cf0 @ Wel[H:], exists logits. grid 128 (m) x 256 (h).
// ---------------------------------------------------------------------------
__global__ void __launch_bounds__(256) k_ab(
    const float* __restrict__ cf0, const float* __restrict__ Wel,
    const float* __restrict__ Wex, const float* __restrict__ bex,
    float* __restrict__ A, float* __restrict__ B,
    float* __restrict__ out_ex)
{
  const int m = blockIdx.x, h = threadIdx.x;
  __shared__ float scf[256];
  __shared__ float red[256];
  const float cv = cf0[m * 256 + h];
  scf[h] = cv;
  __syncthreads();
  float a = 0.f, b = 0.f;
  #pragma unroll 4
  for (int k = 0; k < 256; ++k) {
    const float c = scf[k];
    a = fmaf(c, Wel[k * 256 + h], a);
    b = fmaf(c, Wel[(256 + k) * 256 + h], b);
  }
  A[m * 256 + h] = a;
  B[m * 256 + h] = b;
  red[h] = cv * Wex[h];
  __syncthreads();
  for (int s = 128; s > 0; s >>= 1) {
    if (h < s) red[h] += red[h + s];
    __syncthreads();
  }
  if (h == 0) out_ex[m] = red[0] + bex[0];
}

// ---------------------------------------------------------------------------
// K3: ee[i,j,t] = sum_h relu(A[i,h]+B[j,h]+bel[h]) * Wee[t,h] + bee[t]
// grid 128 (i), 256 thr = 4 waves; wave w handles j = w + 4*jj; lane l owns
// k in {l, l+64, l+128, l+192}. fp32 exact (mask depends on sign of ee).
// ---------------------------------------------------------------------------
__global__ void __launch_bounds__(256) k_ee(
    const float* __restrict__ A, const float* __restrict__ B,
    const float* __restrict__ bel, const float* __restrict__ Wee,
    const float* __restrict__ bee, float* __restrict__ out_ee)
{
  const int i = blockIdx.x;
  const int w = threadIdx.x >> 6, l = threadIdx.x & 63;
  float a[4], bl[4], we0[4], we1[4], we2[4], we3[4];
  #pragma unroll
  for (int q = 0; q < 4; ++q) {
    a[q]  = A[i * 256 + q * 64 + l];
    bl[q] = bel[q * 64 + l];
    we0[q] = Wee[0 * 256 + q * 64 + l];
    we1[q] = Wee[1 * 256 + q * 64 + l];
    we2[q] = Wee[2 * 256 + q * 64 + l];
    we3[q] = Wee[3 * 256 + q * 64 + l];
  }
  const float be0 = bee[0], be1 = bee[1], be2 = bee[2], be3 = bee[3];
  for (int jj = 0; jj < 32; ++jj) {
    const int j = w + jj * 4;
    float s0 = 0.f, s1 = 0.f, s2 = 0.f, s3 = 0.f;
    #pragma unroll
    for (int q = 0; q < 4; ++q) {
      const float e = fmaxf(a[q] + bl[q] + B[j * 256 + q * 64 + l], 0.f);
      s0 = fmaf(e, we0[q], s0);
      s1 = fmaf(e, we1[q], s1);
      s2 = fmaf(e, we2[q], s2);
      s3 = fmaf(e, we3[q], s3);
    }
    for (int off = 32; off > 0; off >>= 1) {
      s0 += __shfl_xor(s0, off);
      s1 += __shfl_xor(s1, off);
      s2 += __shfl_xor(s2, off);
      s3 += __shfl_xor(s3, off);
    }
    if (l < 4) {
      const float v = (l == 0) ? (s0 + be0) : (l == 1) ? (s1 + be1)
                     : (l == 2) ? (s2 + be2) : (s3 + be3);
      out_ee[(i * 128 + j) * 4 + l] = v;
    }
  }
}

// ---------------------------------------------------------------------------
// K4a: a1 = cf @ W_op[i,:H], a2 = cf @ W_op[i,H:2H]. grid 128 (m) x 256 (h).
// ---------------------------------------------------------------------------
__global__ void __launch_bounds__(256) k_a12(
    const float* __restrict__ cf, const float* __restrict__ Wop_it,
    float* __restrict__ a1, float* __restrict__ a2)
{
  const int m = blockIdx.x, h = threadIdx.x;
  __shared__ float scf[256];
  scf[h] = cf[m * 256 + h];
  __syncthreads();
  float x = 0.f, y = 0.f;
  #pragma unroll 4
  for (int k = 0; k < 256; ++k) {
    const float c = scf[k];
    x = fmaf(c, Wop_it[k * 256 + h], x);
    y = fmaf(c, Wop_it[(256 + k) * 256 + h], y);
  }
  a1[m * 256 + h] = x;
  a2[m * 256 + h] = y;
}

// ---------------------------------------------------------------------------
// K4b: heavy op kernel. grid 512 = (i, j-quarter), 256 thr = 4 wave-groups.
// Group jg (one wave) handles 8 j's as 2 quads; thread owns 4 contiguous cols.
// C_ij = el_ij @ W3 (el recomputed from A,B rows); fused masked relu-max epi.
// Partial max per (i,jq) -> part_op.
// ---------------------------------------------------------------------------
#define OP_EPI(J, C) do { \
  float4 pb = add4(add4(base1, ld4(a2 + (J) * 256 + cb)), (C)); \
  if (exi && (exlog[(J)] > 0.f)) { \
    const float e0 = eei[(J) * 4 + 0], e1 = eei[(J) * 4 + 1]; \
    const float e2 = eei[(J) * 4 + 2], e3 = eei[(J) * 4 + 3]; \
    if (e0 > 0.f) acc = max4(acc, relu4(fma4(e0, w4r0, pb))); \
    if (e1 > 0.f) acc = max4(acc, relu4(fma4(e1, w4r1, pb))); \
    if (e2 > 0.f) acc = max4(acc, relu4(fma4(e2, w4r2, pb))); \
    if (e3 > 0.f) acc = max4(acc, relu4(fma4(e3, w4r3, pb))); \
  } \
} while (0)

__global__ void __launch_bounds__(256) k_op(
    const float* __restrict__ A, const float* __restrict__ B,
    const float* __restrict__ bel,
    const float* __restrict__ a1, const float* __restrict__ a2,
    const float* __restrict__ Wop_it, const float* __restrict__ bop_it,
    const float* __restrict__ ee, const float* __restrict__ exlog,
    float* __restrict__ part_op)
{
  const int i = blockIdx.x >> 2, jq = blockIdx.x & 3;
  const int jg = threadIdx.x >> 6, hq = threadIdx.x & 63;
  const int cb = hq << 2;
  __shared__ float els[4][4][256];   // [group][j-in-quad][k]
  __shared__ float red[4][256];

  const float4 ab    = add4(ld4(A + i * 256 + cb), ld4(bel + cb));
  const float4 base1 = add4(ld4(a1 + i * 256 + cb), ld4(bop_it + cb));
  const float4 w4r0 = ld4(Wop_it + (768 + 0) * 256 + cb);
  const float4 w4r1 = ld4(Wop_it + (768 + 1) * 256 + cb);
  const float4 w4r2 = ld4(Wop_it + (768 + 2) * 256 + cb);
  const float4 w4r3 = ld4(Wop_it + (768 + 3) * 256 + cb);
  const bool exi = exlog[i] > 0.f;
  const float* W3  = Wop_it + 512 * 256;
  const float* eei = ee + i * 512;
  float4 acc = make_float4(0.f, 0.f, 0.f, 0.f);

  for (int p = 0; p < 2; ++p) {
    const int jb = jq * 32 + jg * 8 + p * 4;
    #pragma unroll
    for (int q = 0; q < 4; ++q) {
      float4 e = relu4(add4(ab, ld4(B + (jb + q) * 256 + cb)));
      st4(&els[jg][q][cb], e);
    }
    __syncthreads();
    float4 c0 = make_float4(0.f, 0.f, 0.f, 0.f);
    float4 c1 = c0, c2 = c0, c3 = c0;
    for (int k = 0; k < 256; k += 4) {
      union U { float4 v; float f[4]; } ea, eb, ec, ed;
      ea.v = ld4(&els[jg][0][k]);
      eb.v = ld4(&els[jg][1][k]);
      ec.v = ld4(&els[jg][2][k]);
      ed.v = ld4(&els[jg][3][k]);
      const float* wp = W3 + k * 256 + cb;
      #pragma unroll
      for (int kk = 0; kk < 4; ++kk) {
        const float4 wv = ld4(wp + kk * 256);
        c0 = fma4(ea.f[kk], wv, c0);
        c1 = fma4(eb.f[kk], wv, c1);
        c2 = fma4(ec.f[kk], wv, c2);
        c3 = fma4(ed.f[kk], wv, c3);
      }
    }
    OP_EPI(jb + 0, c0);
    OP_EPI(jb + 1, c1);
    OP_EPI(jb + 2, c2);
    OP_EPI(jb + 3, c3);
    __syncthreads();
  }
  st4(&red[jg][cb], acc);
  __syncthreads();
  if (jg == 0) {
    float4 r0 = ld4(&red[0][cb]), r1 = ld4(&red[1][cb]);
    float4 r2 = ld4(&red[2][cb]), r3 = ld4(&red[3][cb]);
    st4(&part_op[(i * 4 + jq) * 256 + cb], max4(max4(r0, r1), max4(r2, r3)));
  }
}

// K4c: combine j-quarter partial maxes -> cf_next. grid 128 x 256.
__global__ void __launch_bounds__(256) k_op_combine(
    const float* __restrict__ part_op, float* __restrict__ cfn)
{
  const int idx = blockIdx.x * 256 + threadIdx.x;
  const int m = idx >> 8, h = idx & 255;
  float v = part_op[(m * 4 + 0) * 256 + h];
  v = fmaxf(v, part_op[(m * 4 + 1) * 256 + h]);
  v = fmaxf(v, part_op[(m * 4 + 2) * 256 + h]);
  v = fmaxf(v, part_op[(m * 4 + 3) * 256 + h]);
  cfn[idx] = v;
}

// ---------------------------------------------------------------------------
// K5: ch = relu(allf @ Wch + bch); sem = ch @ Wsem + bsem;
//     feats = relu(ch @ Wch2 + bch2). grid 128 (m) x 256 (h).
// ---------------------------------------------------------------------------
__global__ void __launch_bounds__(256) k_final(
    const float* __restrict__ cf0, const float* __restrict__ cf1,
    const float* __restrict__ cf2,
    const float* __restrict__ Wch, const float* __restrict__ bch,
    const float* __restrict__ Wsem, const float* __restrict__ bsem,
    const float* __restrict__ Wch2, const float* __restrict__ bch2,
    float* __restrict__ out_feats, float* __restrict__ out_sem)
{
  const int m = blockIdx.x, h = threadIdx.x;
  __shared__ float sall[768];
  __shared__ float sch[256];
  sall[h]       = cf0[m * 256 + h];
  sall[256 + h] = cf1[m * 256 + h];
  sall[512 + h] = cf2[m * 256 + h];
  __syncthreads();
  float acc = bch[h];
  #pragma unroll 4
  for (int k = 0; k < 768; ++k)
    acc = fmaf(sall[k], Wch[k * 256 + h], acc);
  const float chv = fmaxf(acc, 0.f);
  sch[h] = chv;
  __syncthreads();
  float f = bch2[h];
  #pragma unroll 4
  for (int k = 0; k < 256; ++k)
    f = fmaf(sch[k], Wch2[k * 256 + h], f);
  out_feats[m * 256 + h] = fmaxf(f, 0.f);
  if (h < 57) {
    float s = bsem[h];
    for (int k = 0; k < 256; ++k)
      s = fmaf(sch[k], Wsem[k * 57 + h], s);
    out_sem[m * 57 + h] = s;  // no relu on sem logits
  }
}

// ---------------------------------------------------------------------------
extern "C" void kernel_launch(void* const* d_in, const int* in_sizes, int n_in,
                              void* d_out, int out_size, void* d_ws, size_t ws_size,
                              hipStream_t stream)
{
  const float* pf   = (const float*)d_in[0];
  const float* Wp   = (const float*)d_in[1];
  const float* bp   = (const float*)d_in[2];
  const float* Wex  = (const float*)d_in[3];
  const float* bex  = (const float*)d_in[4];
  const float* Wel  = (const float*)d_in[5];
  const float* bel  = (const float*)d_in[6];
  const float* Wee  = (const float*)d_in[7];
  const float* bee  = (const float*)d_in[8];
  const float* Wop  = (const float*)d_in[9];
  const float* bop  = (const float*)d_in[10];
  const float* Wch  = (const float*)d_in[11];
  const float* bch  = (const float*)d_in[12];
  const float* Wsem = (const float*)d_in[13];
  const float* bsem = (const float*)d_in[14];
  const float* Wch2 = (const float*)d_in[15];
  const float* bch2 = (const float*)d_in[16];

  // Output layout (fp32): feats (128*256) | sem (128*57) | exists (128) | ee (128*128*4)
  float* out_feats = (float*)d_out;
  float* out_sem   = out_feats + M_ * F_;
  float* out_ex    = out_sem + M_ * NSEM_;
  float* out_ee    = out_ex + M_;

  // Workspace (floats): ~1.7 MB total
  float* ws = (float*)d_ws;
  float* cf0 = ws;                 // 32768
  float* cf1 = ws + 32768;         // 32768
  float* cf2 = ws + 65536;         // 32768
  float* Ab  = ws + 98304;         // 32768
  float* Bb  = ws + 131072;        // 32768
  float* a1  = ws + 163840;        // 32768
  float* a2  = ws + 196608;        // 32768
  float* part    = ws + 229376;    // 65536
  float* part_op = ws + 294912;    // 131072

  k_parent_partial<<<256, 256, 0, stream>>>(pf, Wp, part);
  k_parent_combine<<<128, 256, 0, stream>>>(part, bp, cf0);
  k_ab<<<128, 256, 0, stream>>>(cf0, Wel, Wex, bex, Ab, Bb, out_ex);
  k_ee<<<128, 256, 0, stream>>>(Ab, Bb, bel, Wee, bee, out_ee);

  float* cfs[3] = {cf0, cf1, cf2};
  for (int it = 0; it < 2; ++it) {
    const float* Wop_it = Wop + (size_t)it * 772 * 256;
    const float* bop_it = bop + it * 256;
    k_a12<<<128, 256, 0, stream>>>(cfs[it], Wop_it, a1, a2);
    k_op<<<512, 256, 0, stream>>>(Ab, Bb, bel, a1, a2, Wop_it, bop_it,
                                  out_ee, out_ex, part_op);
    k_op_combine<<<128, 256, 0, stream>>>(part_op, cfs[it + 1]);
  }
  k_final<<<128, 256, 0, stream>>>(cf0, cf1, cf2, Wch, bch, Wsem, bsem,
                                   Wch2, bch2, out_feats, out_sem);
}

// Round 2
// 210.396 us; speedup vs baseline: 1.2697x; 1.2697x over previous
//
#include <hip/hip_runtime.h>
#include <hip/hip_bf16.h>

// Shapes: M=128, H=256, F=256, T=4, I=2, NSEM=57
#define M_ 128
#define H_ 256
#define F_ 256
#define T_ 4
#define NSEM_ 57

__device__ __forceinline__ float4 ld4(const float* p) { return *reinterpret_cast<const float4*>(p); }
__device__ __forceinline__ void st4(float* p, float4 v) { *reinterpret_cast<float4*>(p) = v; }
__device__ __forceinline__ float4 add4(float4 a, float4 b) { return make_float4(a.x+b.x, a.y+b.y, a.z+b.z, a.w+b.w); }
__device__ __forceinline__ float4 relu4(float4 a) { return make_float4(fmaxf(a.x,0.f), fmaxf(a.y,0.f), fmaxf(a.z,0.f), fmaxf(a.w,0.f)); }
__device__ __forceinline__ float4 max4(float4 a, float4 b) { return make_float4(fmaxf(a.x,b.x), fmaxf(a.y,b.y), fmaxf(a.z,b.z), fmaxf(a.w,b.w)); }
__device__ __forceinline__ float4 fma4(float s, float4 w, float4 c) { return make_float4(fmaf(s,w.x,c.x), fmaf(s,w.y,c.y), fmaf(s,w.z,c.z), fmaf(s,w.w,c.w)); }

// ---------------------------------------------------------------------------
// K1a: partial parent matmul. grid 256 = 32 col-blocks (1024 cols) x 8 k-chunks
// (32 k each), 256 thr. Each thread: float4 column quad, 32 serial ld4.
// part[kc*32768 + col] = sum_{k in chunk} pf[k] * Wp[k*32768 + col]
// ---------------------------------------------------------------------------
__global__ void __launch_bounds__(256) k_parent_partial(
    const float* __restrict__ pf, const float* __restrict__ Wp,
    float* __restrict__ part)
{
  const int cb = (blockIdx.x & 31) * 1024 + threadIdx.x * 4;
  const int kc = blockIdx.x >> 5;
  __shared__ float spf[32];
  if (threadIdx.x < 32) spf[threadIdx.x] = pf[kc * 32 + threadIdx.x];
  __syncthreads();
  const float* w = Wp + (size_t)kc * 32 * 32768 + cb;
  float4 acc = make_float4(0.f, 0.f, 0.f, 0.f);
  #pragma unroll 8
  for (int k = 0; k < 32; ++k)
    acc = fma4(spf[k], ld4(w + (size_t)k * 32768), acc);
  st4(&part[kc * 32768 + cb], acc);
}

// K1b: combine 8 partials + bias + relu -> cf0. grid 32 x 256 (float4).
__global__ void __launch_bounds__(256) k_parent_combine(
    const float* __restrict__ part, const float* __restrict__ bp,
    float* __restrict__ cf0)
{
  const int c4 = (blockIdx.x * 256 + threadIdx.x) * 4;
  float4 v = ld4(bp + c4);
  #pragma unroll
  for (int q = 0; q < 8; ++q)
    v = add4(v, ld4(part + q * 32768 + c4));
  st4(&cf0[c4], relu4(v));
}

// ---------------------------------------------------------------------------
// K2: A = cf0 @ Wel[:H], B = cf0 @ Wel[H:], exists logits. grid 128 (m) x 256 (h).
// ---------------------------------------------------------------------------
__global__ void __launch_bounds__(256) k_ab(
    const float* __restrict__ cf0, const float* __restrict__ Wel,
    const float* __restrict__ Wex, const float* __restrict__ bex,
    float* __restrict__ A, float* __restrict__ B,
    float* __restrict__ out_ex)
{
  const int m = blockIdx.x, h = threadIdx.x;
  __shared__ float scf[256];
  __shared__ float red[256];
  const float cv = cf0[m * 256 + h];
  scf[h] = cv;
  __syncthreads();
  float a = 0.f, b = 0.f;
  #pragma unroll 4
  for (int k = 0; k < 256; ++k) {
    const float c = scf[k];
    a = fmaf(c, Wel[k * 256 + h], a);
    b = fmaf(c, Wel[(256 + k) * 256 + h], b);
  }
  A[m * 256 + h] = a;
  B[m * 256 + h] = b;
  red[h] = cv * Wex[h];
  __syncthreads();
  for (int s = 128; s > 0; s >>= 1) {
    if (h < s) red[h] += red[h + s];
    __syncthreads();
  }
  if (h == 0) out_ex[m] = red[0] + bex[0];
}

// ---------------------------------------------------------------------------
// K3: ee[i,j,t] = sum_h relu(A[i,h]+B[j,h]+bel[h]) * Wee[t,h] + bee[t]
// grid 128 (i), 256 thr = 4 waves; wave w handles j = w + 4*jj; lane l owns
// k in {l, l+64, l+128, l+192}. fp32 exact (mask depends on sign of ee).
// ---------------------------------------------------------------------------
__global__ void __launch_bounds__(256) k_ee(
    const float* __restrict__ A, const float* __restrict__ B,
    const float* __restrict__ bel, const float* __restrict__ Wee,
    const float* __restrict__ bee, float* __restrict__ out_ee)
{
  const int i = blockIdx.x;
  const int w = threadIdx.x >> 6, l = threadIdx.x & 63;
  float a[4], bl[4], we0[4], we1[4], we2[4], we3[4];
  #pragma unroll
  for (int q = 0; q < 4; ++q) {
    a[q]  = A[i * 256 + q * 64 + l];
    bl[q] = bel[q * 64 + l];
    we0[q] = Wee[0 * 256 + q * 64 + l];
    we1[q] = Wee[1 * 256 + q * 64 + l];
    we2[q] = Wee[2 * 256 + q * 64 + l];
    we3[q] = Wee[3 * 256 + q * 64 + l];
  }
  const float be0 = bee[0], be1 = bee[1], be2 = bee[2], be3 = bee[3];
  for (int jj = 0; jj < 32; ++jj) {
    const int j = w + jj * 4;
    float s0 = 0.f, s1 = 0.f, s2 = 0.f, s3 = 0.f;
    #pragma unroll
    for (int q = 0; q < 4; ++q) {
      const float e = fmaxf(a[q] + bl[q] + B[j * 256 + q * 64 + l], 0.f);
      s0 = fmaf(e, we0[q], s0);
      s1 = fmaf(e, we1[q], s1);
      s2 = fmaf(e, we2[q], s2);
      s3 = fmaf(e, we3[q], s3);
    }
    for (int off = 32; off > 0; off >>= 1) {
      s0 += __shfl_xor(s0, off);
      s1 += __shfl_xor(s1, off);
      s2 += __shfl_xor(s2, off);
      s3 += __shfl_xor(s3, off);
    }
    if (l < 4) {
      const float v = (l == 0) ? (s0 + be0) : (l == 1) ? (s1 + be1)
                     : (l == 2) ? (s2 + be2) : (s3 + be3);
      out_ee[(i * 128 + j) * 4 + l] = v;
    }
  }
}

// ---------------------------------------------------------------------------
// K4a: a1 = cf @ W_op[i,:H], a2 = cf @ W_op[i,H:2H]. grid 128 (m) x 256 (h).
// ---------------------------------------------------------------------------
__global__ void __launch_bounds__(256) k_a12(
    const float* __restrict__ cf, const float* __restrict__ Wop_it,
    float* __restrict__ a1, float* __restrict__ a2)
{
  const int m = blockIdx.x, h = threadIdx.x;
  __shared__ float scf[256];
  scf[h] = cf[m * 256 + h];
  __syncthreads();
  float x = 0.f, y = 0.f;
  #pragma unroll 4
  for (int k = 0; k < 256; ++k) {
    const float c = scf[k];
    x = fmaf(c, Wop_it[k * 256 + h], x);
    y = fmaf(c, Wop_it[(256 + k) * 256 + h], y);
  }
  a1[m * 256 + h] = x;
  a2[m * 256 + h] = y;
}

// ---------------------------------------------------------------------------
// K4b: heavy op kernel. grid 512 = (i, j-quarter), 256 thr = 4 wave-groups.
// Group jg (one wave) handles 8 j's as 2 quads; thread owns 4 contiguous cols.
// C_ij = el_ij @ W3 (el recomputed from A,B rows); fused masked relu-max epi.
// Partial max per (i,jq) -> part_op.
// ---------------------------------------------------------------------------
#define OP_EPI(J, C) do { \
  float4 pb = add4(add4(base1, ld4(a2 + (J) * 256 + cb)), (C)); \
  if (exi && (exlog[(J)] > 0.f)) { \
    const float e0 = eei[(J) * 4 + 0], e1 = eei[(J) * 4 + 1]; \
    const float e2 = eei[(J) * 4 + 2], e3 = eei[(J) * 4 + 3]; \
    if (e0 > 0.f) acc = max4(acc, relu4(fma4(e0, w4r0, pb))); \
    if (e1 > 0.f) acc = max4(acc, relu4(fma4(e1, w4r1, pb))); \
    if (e2 > 0.f) acc = max4(acc, relu4(fma4(e2, w4r2, pb))); \
    if (e3 > 0.f) acc = max4(acc, relu4(fma4(e3, w4r3, pb))); \
  } \
} while (0)

__global__ void __launch_bounds__(256) k_op(
    const float* __restrict__ A, const float* __restrict__ B,
    const float* __restrict__ bel,
    const float* __restrict__ a1, const float* __restrict__ a2,
    const float* __restrict__ Wop_it, const float* __restrict__ bop_it,
    const float* __restrict__ ee, const float* __restrict__ exlog,
    float* __restrict__ part_op)
{
  const int i = blockIdx.x >> 2, jq = blockIdx.x & 3;
  const int jg = threadIdx.x >> 6, hq = threadIdx.x & 63;
  const int cb = hq << 2;
  __shared__ float els[4][4][256];   // [group][j-in-quad][k]
  __shared__ float red[4][256];

  const float4 ab    = add4(ld4(A + i * 256 + cb), ld4(bel + cb));
  const float4 base1 = add4(ld4(a1 + i * 256 + cb), ld4(bop_it + cb));
  const float4 w4r0 = ld4(Wop_it + (768 + 0) * 256 + cb);
  const float4 w4r1 = ld4(Wop_it + (768 + 1) * 256 + cb);
  const float4 w4r2 = ld4(Wop_it + (768 + 2) * 256 + cb);
  const float4 w4r3 = ld4(Wop_it + (768 + 3) * 256 + cb);
  const bool exi = exlog[i] > 0.f;
  const float* W3  = Wop_it + 512 * 256;
  const float* eei = ee + i * 512;
  float4 acc = make_float4(0.f, 0.f, 0.f, 0.f);

  for (int p = 0; p < 2; ++p) {
    const int jb = jq * 32 + jg * 8 + p * 4;
    #pragma unroll
    for (int q = 0; q < 4; ++q) {
      float4 e = relu4(add4(ab, ld4(B + (jb + q) * 256 + cb)));
      st4(&els[jg][q][cb], e);
    }
    __syncthreads();
    float4 c0 = make_float4(0.f, 0.f, 0.f, 0.f);
    float4 c1 = c0, c2 = c0, c3 = c0;
    for (int k = 0; k < 256; k += 4) {
      union U { float4 v; float f[4]; } ea, eb, ec, ed;
      ea.v = ld4(&els[jg][0][k]);
      eb.v = ld4(&els[jg][1][k]);
      ec.v = ld4(&els[jg][2][k]);
      ed.v = ld4(&els[jg][3][k]);
      const float* wp = W3 + k * 256 + cb;
      #pragma unroll
      for (int kk = 0; kk < 4; ++kk) {
        const float4 wv = ld4(wp + kk * 256);
        c0 = fma4(ea.f[kk], wv, c0);
        c1 = fma4(eb.f[kk], wv, c1);
        c2 = fma4(ec.f[kk], wv, c2);
        c3 = fma4(ed.f[kk], wv, c3);
      }
    }
    OP_EPI(jb + 0, c0);
    OP_EPI(jb + 1, c1);
    OP_EPI(jb + 2, c2);
    OP_EPI(jb + 3, c3);
    __syncthreads();
  }
  st4(&red[jg][cb], acc);
  __syncthreads();
  if (jg == 0) {
    float4 r0 = ld4(&red[0][cb]), r1 = ld4(&red[1][cb]);
    float4 r2 = ld4(&red[2][cb]), r3 = ld4(&red[3][cb]);
    st4(&part_op[(i * 4 + jq) * 256 + cb], max4(max4(r0, r1), max4(r2, r3)));
  }
}

// K4c: combine j-quarter partial maxes -> cf_next. grid 128 x 256.
__global__ void __launch_bounds__(256) k_op_combine(
    const float* __restrict__ part_op, float* __restrict__ cfn)
{
  const int idx = blockIdx.x * 256 + threadIdx.x;
  const int m = idx >> 8, h = idx & 255;
  float v = part_op[(m * 4 + 0) * 256 + h];
  v = fmaxf(v, part_op[(m * 4 + 1) * 256 + h]);
  v = fmaxf(v, part_op[(m * 4 + 2) * 256 + h]);
  v = fmaxf(v, part_op[(m * 4 + 3) * 256 + h]);
  cfn[idx] = v;
}

// ---------------------------------------------------------------------------
// K5: ch = relu(allf @ Wch + bch); sem = ch @ Wsem + bsem;
//     feats = relu(ch @ Wch2 + bch2).
// grid 128 (m) x 256 thr. K split across 4 waves (kg = wave id), H vectorized
// float4 (hq = (t&63)*4): stage-1 = 192 independent ld4/thread, LDS reduce.
// Fixes R1's latency-bound k_final (119us, VALUBusy 1%, 1 scalar load/iter).
// ---------------------------------------------------------------------------
__global__ void __launch_bounds__(256) k_final(
    const float* __restrict__ cf0, const float* __restrict__ cf1,
    const float* __restrict__ cf2,
    const float* __restrict__ Wch, const float* __restrict__ bch,
    const float* __restrict__ Wsem, const float* __restrict__ bsem,
    const float* __restrict__ Wch2, const float* __restrict__ bch2,
    float* __restrict__ out_feats, float* __restrict__ out_sem)
{
  const int m  = blockIdx.x;
  const int t  = threadIdx.x;
  const int hq = (t & 63) << 2;   // 0,4,...,252 (float4 col quad)
  const int kg = t >> 6;          // wave id = k-group
  __shared__ float sall[768];
  __shared__ float sch[256];
  __shared__ float red[4][256];
  __shared__ float redS[4][64];

  sall[t]       = cf0[m * 256 + t];
  sall[256 + t] = cf1[m * 256 + t];
  sall[512 + t] = cf2[m * 256 + t];
  __syncthreads();

  // ---- stage 1: ch = relu(allf @ Wch + bch), K=768 split 4x192
  {
    float4 acc = make_float4(0.f, 0.f, 0.f, 0.f);
    const int k0 = kg * 192;
    #pragma unroll 8
    for (int k = k0; k < k0 + 192; ++k)
      acc = fma4(sall[k], ld4(Wch + k * 256 + hq), acc);
    st4(&red[kg][hq], acc);
  }
  __syncthreads();
  if (kg == 0) {
    float4 r = add4(add4(ld4(&red[0][hq]), ld4(&red[1][hq])),
                    add4(ld4(&red[2][hq]), ld4(&red[3][hq])));
    r = relu4(add4(r, ld4(bch + hq)));
    st4(&sch[hq], r);
  }
  __syncthreads();

  // ---- stage 2: feats = relu(ch @ Wch2 + bch2), K=256 split 4x64
  {
    float4 f = make_float4(0.f, 0.f, 0.f, 0.f);
    const int k0 = kg * 64;
    #pragma unroll 8
    for (int k = k0; k < k0 + 64; ++k)
      f = fma4(sch[k], ld4(Wch2 + k * 256 + hq), f);
    // stage-3 partials computed before touching red again (separate redS)
    const int s = t & 63;
    float sv = 0.f;
    if (s < 57) {
      #pragma unroll 8
      for (int k = k0; k < k0 + 64; ++k)
        sv = fmaf(sch[k], Wsem[k * 57 + s], sv);
    }
    redS[kg][s] = sv;
    __syncthreads();   // red free to overwrite (last read was before prev sync)
    st4(&red[kg][hq], f);
  }
  __syncthreads();
  if (kg == 0) {
    float4 r = add4(add4(ld4(&red[0][hq]), ld4(&red[1][hq])),
                    add4(ld4(&red[2][hq]), ld4(&red[3][hq])));
    r = relu4(add4(r, ld4(bch2 + hq)));
    st4(&out_feats[m * 256 + hq], r);
    const int s = t & 63;
    if (s < 57)
      out_sem[m * 57 + s] = redS[0][s] + redS[1][s] + redS[2][s] + redS[3][s]
                          + bsem[s];
  }
}

// ---------------------------------------------------------------------------
extern "C" void kernel_launch(void* const* d_in, const int* in_sizes, int n_in,
                              void* d_out, int out_size, void* d_ws, size_t ws_size,
                              hipStream_t stream)
{
  const float* pf   = (const float*)d_in[0];
  const float* Wp   = (const float*)d_in[1];
  const float* bp   = (const float*)d_in[2];
  const float* Wex  = (const float*)d_in[3];
  const float* bex  = (const float*)d_in[4];
  const float* Wel  = (const float*)d_in[5];
  const float* bel  = (const float*)d_in[6];
  const float* Wee  = (const float*)d_in[7];
  const float* bee  = (const float*)d_in[8];
  const float* Wop  = (const float*)d_in[9];
  const float* bop  = (const float*)d_in[10];
  const float* Wch  = (const float*)d_in[11];
  const float* bch  = (const float*)d_in[12];
  const float* Wsem = (const float*)d_in[13];
  const float* bsem = (const float*)d_in[14];
  const float* Wch2 = (const float*)d_in[15];
  const float* bch2 = (const float*)d_in[16];

  // Output layout (fp32): feats (128*256) | sem (128*57) | exists (128) | ee (128*128*4)
  float* out_feats = (float*)d_out;
  float* out_sem   = out_feats + M_ * F_;
  float* out_ex    = out_sem + M_ * NSEM_;
  float* out_ee    = out_ex + M_;

  // Workspace (floats): part (8*32768) overlaps part_op in time -> ~1.9 MB
  float* ws = (float*)d_ws;
  float* cf0 = ws;                 // 32768
  float* cf1 = ws + 32768;         // 32768
  float* cf2 = ws + 65536;         // 32768
  float* Ab  = ws + 98304;         // 32768
  float* Bb  = ws + 131072;        // 32768
  float* a1  = ws + 163840;        // 32768
  float* a2  = ws + 196608;        // 32768
  float* part    = ws + 229376;    // 262144 (8 k-chunks), dead after combine
  float* part_op = ws + 229376;    // 131072 (reuses part region)

  k_parent_partial<<<256, 256, 0, stream>>>(pf, Wp, part);
  k_parent_combine<<<32, 256, 0, stream>>>(part, bp, cf0);
  k_ab<<<128, 256, 0, stream>>>(cf0, Wel, Wex, bex, Ab, Bb, out_ex);
  k_ee<<<128, 256, 0, stream>>>(Ab, Bb, bel, Wee, bee, out_ee);

  float* cfs[3] = {cf0, cf1, cf2};
  for (int it = 0; it < 2; ++it) {
    const float* Wop_it = Wop + (size_t)it * 772 * 256;
    const float* bop_it = bop + it * 256;
    k_a12<<<128, 256, 0, stream>>>(cfs[it], Wop_it, a1, a2);
    k_op<<<512, 256, 0, stream>>>(Ab, Bb, bel, a1, a2, Wop_it, bop_it,
                                  out_ee, out_ex, part_op);
    k_op_combine<<<128, 256, 0, stream>>>(part_op, cfs[it + 1]);
  }
  k_final<<<128, 256, 0, stream>>>(cf0, cf1, cf2, Wch, bch, Wsem, bsem,
                                   Wch2, bch2, out_feats, out_sem);
}

// Round 3
// 138.155 us; speedup vs baseline: 1.9337x; 1.5229x over previous
//
#include <hip/hip_runtime.h>
#include <hip/hip_bf16.h>

// Shapes: M=128, H=256, F=256, T=4, I=2, NSEM=57
#define M_ 128
#define H_ 256
#define F_ 256
#define T_ 4
#define NSEM_ 57

typedef __attribute__((ext_vector_type(8))) short bf16x8;
typedef __attribute__((ext_vector_type(4))) float f32x4;

__device__ __forceinline__ float4 ld4(const float* p) { return *reinterpret_cast<const float4*>(p); }
__device__ __forceinline__ void st4(float* p, float4 v) { *reinterpret_cast<float4*>(p) = v; }
__device__ __forceinline__ float4 add4(float4 a, float4 b) { return make_float4(a.x+b.x, a.y+b.y, a.z+b.z, a.w+b.w); }
__device__ __forceinline__ float4 relu4(float4 a) { return make_float4(fmaxf(a.x,0.f), fmaxf(a.y,0.f), fmaxf(a.z,0.f), fmaxf(a.w,0.f)); }
__device__ __forceinline__ float4 fma4(float s, float4 w, float4 c) { return make_float4(fmaf(s,w.x,c.x), fmaf(s,w.y,c.y), fmaf(s,w.z,c.z), fmaf(s,w.w,c.w)); }

__device__ __forceinline__ unsigned short f2bfu(float x) {
  unsigned u = __float_as_uint(x);
  return (unsigned short)((u + 0x7FFFu + ((u >> 16) & 1u)) >> 16);  // RNE
}
__device__ __forceinline__ float bfu2f(unsigned short b) {
  return __uint_as_float(((unsigned)b) << 16);
}
__device__ __forceinline__ unsigned pack2(float lo, float hi) {
  return (unsigned)f2bfu(lo) | ((unsigned)f2bfu(hi) << 16);
}

// ---------------------------------------------------------------------------
// K1a: partial parent matmul. grid 256 = 32 col-blocks x 8 k-chunks, 256 thr.
// ---------------------------------------------------------------------------
__global__ void __launch_bounds__(256) k_parent_partial(
    const float* __restrict__ pf, const float* __restrict__ Wp,
    float* __restrict__ part)
{
  const int cb = (blockIdx.x & 31) * 1024 + threadIdx.x * 4;
  const int kc = blockIdx.x >> 5;
  __shared__ float spf[32];
  if (threadIdx.x < 32) spf[threadIdx.x] = pf[kc * 32 + threadIdx.x];
  __syncthreads();
  const float* w = Wp + (size_t)kc * 32 * 32768 + cb;
  float4 acc = make_float4(0.f, 0.f, 0.f, 0.f);
  #pragma unroll 8
  for (int k = 0; k < 32; ++k)
    acc = fma4(spf[k], ld4(w + (size_t)k * 32768), acc);
  st4(&part[kc * 32768 + cb], acc);
}

// K1b: combine 8 partials + bias + relu -> cf0. grid 32 x 256 (float4).
__global__ void __launch_bounds__(256) k_parent_combine(
    const float* __restrict__ part, const float* __restrict__ bp,
    float* __restrict__ cf0)
{
  const int c4 = (blockIdx.x * 256 + threadIdx.x) * 4;
  float4 v = ld4(bp + c4);
  #pragma unroll
  for (int q = 0; q < 8; ++q)
    v = add4(v, ld4(part + q * 32768 + c4));
  st4(&cf0[c4], relu4(v));
}

// ---------------------------------------------------------------------------
// K2: A = cf0 @ Wel[:H], B = cf0 @ Wel[H:], exists logits. fp32 exact.
// ---------------------------------------------------------------------------
__global__ void __launch_bounds__(256) k_ab(
    const float* __restrict__ cf0, const float* __restrict__ Wel,
    const float* __restrict__ Wex, const float* __restrict__ bex,
    float* __restrict__ A, float* __restrict__ B,
    float* __restrict__ out_ex)
{
  const int m = blockIdx.x, h = threadIdx.x;
  __shared__ float scf[256];
  __shared__ float red[256];
  const float cv = cf0[m * 256 + h];
  scf[h] = cv;
  __syncthreads();
  float a = 0.f, b = 0.f;
  #pragma unroll 4
  for (int k = 0; k < 256; ++k) {
    const float c = scf[k];
    a = fmaf(c, Wel[k * 256 + h], a);
    b = fmaf(c, Wel[(256 + k) * 256 + h], b);
  }
  A[m * 256 + h] = a;
  B[m * 256 + h] = b;
  red[h] = cv * Wex[h];
  __syncthreads();
  for (int s = 128; s > 0; s >>= 1) {
    if (h < s) red[h] += red[h + s];
    __syncthreads();
  }
  if (h == 0) out_ex[m] = red[0] + bex[0];
}

// ---------------------------------------------------------------------------
// K3: ee fp32 exact (mask depends on sign). grid 512 = (i, j-quarter).
// ---------------------------------------------------------------------------
__global__ void __launch_bounds__(256) k_ee(
    const float* __restrict__ A, const float* __restrict__ B,
    const float* __restrict__ bel, const float* __restrict__ Wee,
    const float* __restrict__ bee, float* __restrict__ out_ee)
{
  const int i = blockIdx.x >> 2, jq = blockIdx.x & 3;
  const int w = threadIdx.x >> 6, l = threadIdx.x & 63;
  float a[4], bl[4], we0[4], we1[4], we2[4], we3[4];
  #pragma unroll
  for (int q = 0; q < 4; ++q) {
    a[q]  = A[i * 256 + q * 64 + l];
    bl[q] = bel[q * 64 + l];
    we0[q] = Wee[0 * 256 + q * 64 + l];
    we1[q] = Wee[1 * 256 + q * 64 + l];
    we2[q] = Wee[2 * 256 + q * 64 + l];
    we3[q] = Wee[3 * 256 + q * 64 + l];
  }
  const float be0 = bee[0], be1 = bee[1], be2 = bee[2], be3 = bee[3];
  for (int jj = 0; jj < 8; ++jj) {
    const int j = jq * 32 + w + jj * 4;
    float s0 = 0.f, s1 = 0.f, s2 = 0.f, s3 = 0.f;
    #pragma unroll
    for (int q = 0; q < 4; ++q) {
      const float e = fmaxf(a[q] + bl[q] + B[j * 256 + q * 64 + l], 0.f);
      s0 = fmaf(e, we0[q], s0);
      s1 = fmaf(e, we1[q], s1);
      s2 = fmaf(e, we2[q], s2);
      s3 = fmaf(e, we3[q], s3);
    }
    for (int off = 32; off > 0; off >>= 1) {
      s0 += __shfl_xor(s0, off);
      s1 += __shfl_xor(s1, off);
      s2 += __shfl_xor(s2, off);
      s3 += __shfl_xor(s3, off);
    }
    if (l < 4) {
      const float v = (l == 0) ? (s0 + be0) : (l == 1) ? (s1 + be1)
                     : (l == 2) ? (s2 + be2) : (s3 + be3);
      out_ee[(i * 128 + j) * 4 + l] = v;
    }
  }
}

// ---------------------------------------------------------------------------
// K_cvt: pack W3 of both iterations into MFMA-b-frag-ordered bf16.
// Frag block fb = (ct_global*8 + kc), ct_global in [0,32) over 512 C-cols,
// kc in [0,8). Element e = l*8+q: value = W3_it[k][h] with
// c = ct*16 + (l&15) (it = c>>8, h = c&255), k = kc*32 + (l>>4)*8 + q.
// grid 256 (fb) x 256 thr (2 elems each). Writes coalesced; reads small.
// ---------------------------------------------------------------------------
__global__ void __launch_bounds__(256) k_cvt_w(
    const float* __restrict__ Wop, unsigned short* __restrict__ W36F)
{
  const int fb = blockIdx.x;
  const int ct = fb >> 3, kc = fb & 7;
  #pragma unroll
  for (int r = 0; r < 2; ++r) {
    const int e = threadIdx.x * 2 + r;
    const int l = e >> 3, q = e & 7;
    const int c = ct * 16 + (l & 15);
    const int k = kc * 32 + (l >> 4) * 8 + q;
    const int it = c >> 8, h = c & 255;
    W36F[fb * 512 + e] = f2bfu(Wop[(size_t)it * 197632 + (512 + k) * 256 + h]);
  }
}

// ---------------------------------------------------------------------------
// K_gemm: C[i,j,0:512] = EL_i[j,:] @ [W3_0 | W3_1]  (bf16 MFMA, fp32 acc).
// grid 512 = (i, j-quarter of 32), 512 thr = 8 waves (wave w: cols w*64..+64).
// EL tile (32x256) computed fp32 -> bf16 into XOR-swizzled LDS (G4 recipe:
// row-major 512B-stride would be 32-way bank conflict on ds_read_b128).
// mfma_f32_16x16x32_bf16; A row=l&15, k=(l>>4)*8; C col=l&15, row=(l>>4)*4+reg.
// ---------------------------------------------------------------------------
__global__ void __launch_bounds__(512) k_gemm(
    const float* __restrict__ Arow, const float* __restrict__ Brow,
    const float* __restrict__ bel, const unsigned short* __restrict__ W36F,
    unsigned short* __restrict__ C)
{
  const int i  = blockIdx.x >> 2;
  const int jq = blockIdx.x & 3;
  const int t  = threadIdx.x;
  const int w  = t >> 6;
  const int l  = t & 63;
  __shared__ char sEL[32 * 512];   // 32 j-rows x 256 k bf16, swizzled

  // ---- stage EL tile: thread -> (row = t>>4, 16 k's at (t&15)*16)
  {
    const int row = t >> 4;
    const int kb  = (t & 15) * 16;
    const float* Ap  = Arow + i * 256 + kb;
    const float* Bp  = Brow + (jq * 32 + row) * 256 + kb;
    const float* blp = bel + kb;
    float e[16];
    #pragma unroll
    for (int q = 0; q < 16; q += 4) {
      float4 av = ld4(Ap + q), bv = ld4(Bp + q), lv = ld4(blp + q);
      e[q+0] = fmaxf(av.x + bv.x + lv.x, 0.f);
      e[q+1] = fmaxf(av.y + bv.y + lv.y, 0.f);
      e[q+2] = fmaxf(av.z + bv.z + lv.z, 0.f);
      e[q+3] = fmaxf(av.w + bv.w + lv.w, 0.f);
    }
    const int swz = (row & 7) << 4;
    uint4 w0, w1;
    w0.x = pack2(e[0], e[1]);  w0.y = pack2(e[2], e[3]);
    w0.z = pack2(e[4], e[5]);  w0.w = pack2(e[6], e[7]);
    w1.x = pack2(e[8], e[9]);  w1.y = pack2(e[10], e[11]);
    w1.z = pack2(e[12], e[13]); w1.w = pack2(e[14], e[15]);
    *reinterpret_cast<uint4*>(sEL + ((row * 512 + kb * 2)      ^ swz)) = w0;
    *reinterpret_cast<uint4*>(sEL + ((row * 512 + kb * 2 + 16) ^ swz)) = w1;
  }
  __syncthreads();

  const int lr = l & 15, lk = l >> 4;
  f32x4 acc[2][4];
  #pragma unroll
  for (int jt = 0; jt < 2; ++jt)
    #pragma unroll
    for (int ct = 0; ct < 4; ++ct)
      acc[jt][ct] = (f32x4){0.f, 0.f, 0.f, 0.f};

  for (int kc = 0; kc < 8; ++kc) {
    const int r0 = lr, r1 = 16 + lr;
    const int kbyte = kc * 64 + lk * 16;
    bf16x8 af0 = *reinterpret_cast<const bf16x8*>(
        sEL + ((r0 * 512 + kbyte) ^ ((r0 & 7) << 4)));
    bf16x8 af1 = *reinterpret_cast<const bf16x8*>(
        sEL + ((r1 * 512 + kbyte) ^ ((r1 & 7) << 4)));
    #pragma unroll
    for (int ct = 0; ct < 4; ++ct) {
      const int fb = (w * 4 + ct) * 8 + kc;
      bf16x8 bf = *reinterpret_cast<const bf16x8*>(W36F + fb * 512 + l * 8);
      acc[0][ct] = __builtin_amdgcn_mfma_f32_16x16x32_bf16(af0, bf, acc[0][ct], 0, 0, 0);
      acc[1][ct] = __builtin_amdgcn_mfma_f32_16x16x32_bf16(af1, bf, acc[1][ct], 0, 0, 0);
    }
  }

  // ---- store C bf16: row j = jq*32 + jt*16 + lk*4 + q, col c = w*64 + ct*16 + lr
  #pragma unroll
  for (int jt = 0; jt < 2; ++jt) {
    #pragma unroll
    for (int ct = 0; ct < 4; ++ct) {
      const int c = w * 64 + ct * 16 + lr;
      #pragma unroll
      for (int q = 0; q < 4; ++q) {
        const int j = jq * 32 + jt * 16 + lk * 4 + q;
        C[(size_t)(i * 128 + j) * 512 + c] = f2bfu(acc[jt][ct][q]);
      }
    }
  }
}

// ---------------------------------------------------------------------------
// K_epi: masked relu-max epilogue per iteration from C.
// grid 512 = (i, jq), 256 thr (h). part_op[(i*4+jq)*256+h] = partial max.
// ---------------------------------------------------------------------------
__global__ void __launch_bounds__(256) k_epi(
    const unsigned short* __restrict__ C, const int itoff,
    const float* __restrict__ a1, const float* __restrict__ a2,
    const float* __restrict__ Wop_it, const float* __restrict__ bop_it,
    const float* __restrict__ ee, const float* __restrict__ exlog,
    float* __restrict__ part_op)
{
  const int i = blockIdx.x >> 2, jq = blockIdx.x & 3;
  const int h = threadIdx.x;
  const float base1 = a1[i * 256 + h] + bop_it[h];
  const float w40 = Wop_it[(768 + 0) * 256 + h];
  const float w41 = Wop_it[(768 + 1) * 256 + h];
  const float w42 = Wop_it[(768 + 2) * 256 + h];
  const float w43 = Wop_it[(768 + 3) * 256 + h];
  float acc = 0.f;
  if (exlog[i] > 0.f) {
    for (int jj = 0; jj < 32; ++jj) {
      const int j = jq * 32 + jj;
      if (exlog[j] > 0.f) {
        const float cv = bfu2f(C[(size_t)(i * 128 + j) * 512 + itoff + h]);
        const float pb = base1 + a2[j * 256 + h] + cv;
        const float e0 = ee[(i * 128 + j) * 4 + 0];
        const float e1 = ee[(i * 128 + j) * 4 + 1];
        const float e2 = ee[(i * 128 + j) * 4 + 2];
        const float e3 = ee[(i * 128 + j) * 4 + 3];
        if (e0 > 0.f) acc = fmaxf(acc, fmaxf(fmaf(e0, w40, pb), 0.f));
        if (e1 > 0.f) acc = fmaxf(acc, fmaxf(fmaf(e1, w41, pb), 0.f));
        if (e2 > 0.f) acc = fmaxf(acc, fmaxf(fmaf(e2, w42, pb), 0.f));
        if (e3 > 0.f) acc = fmaxf(acc, fmaxf(fmaf(e3, w43, pb), 0.f));
      }
    }
  }
  part_op[(i * 4 + jq) * 256 + h] = acc;
}

// K4a: a1 = cf @ W1, a2 = cf @ W2. grid 128 (m) x 256 (h).
__global__ void __launch_bounds__(256) k_a12(
    const float* __restrict__ cf, const float* __restrict__ Wop_it,
    float* __restrict__ a1, float* __restrict__ a2)
{
  const int m = blockIdx.x, h = threadIdx.x;
  __shared__ float scf[256];
  scf[h] = cf[m * 256 + h];
  __syncthreads();
  float x = 0.f, y = 0.f;
  #pragma unroll 4
  for (int k = 0; k < 256; ++k) {
    const float c = scf[k];
    x = fmaf(c, Wop_it[k * 256 + h], x);
    y = fmaf(c, Wop_it[(256 + k) * 256 + h], y);
  }
  a1[m * 256 + h] = x;
  a2[m * 256 + h] = y;
}

// K4c: combine j-quarter partial maxes -> cf_next. grid 128 x 256.
__global__ void __launch_bounds__(256) k_op_combine(
    const float* __restrict__ part_op, float* __restrict__ cfn)
{
  const int idx = blockIdx.x * 256 + threadIdx.x;
  const int m = idx >> 8, h = idx & 255;
  float v = part_op[(m * 4 + 0) * 256 + h];
  v = fmaxf(v, part_op[(m * 4 + 1) * 256 + h]);
  v = fmaxf(v, part_op[(m * 4 + 2) * 256 + h]);
  v = fmaxf(v, part_op[(m * 4 + 3) * 256 + h]);
  cfn[idx] = v;
}

// ---------------------------------------------------------------------------
// K5: ch/sem/feats. K split across 4 waves, float4 cols, LDS reduce.
// ---------------------------------------------------------------------------
__global__ void __launch_bounds__(256) k_final(
    const float* __restrict__ cf0, const float* __restrict__ cf1,
    const float* __restrict__ cf2,
    const float* __restrict__ Wch, const float* __restrict__ bch,
    const float* __restrict__ Wsem, const float* __restrict__ bsem,
    const float* __restrict__ Wch2, const float* __restrict__ bch2,
    float* __restrict__ out_feats, float* __restrict__ out_sem)
{
  const int m  = blockIdx.x;
  const int t  = threadIdx.x;
  const int hq = (t & 63) << 2;
  const int kg = t >> 6;
  __shared__ float sall[768];
  __shared__ float sch[256];
  __shared__ float red[4][256];
  __shared__ float redS[4][64];

  sall[t]       = cf0[m * 256 + t];
  sall[256 + t] = cf1[m * 256 + t];
  sall[512 + t] = cf2[m * 256 + t];
  __syncthreads();

  {
    float4 acc = make_float4(0.f, 0.f, 0.f, 0.f);
    const int k0 = kg * 192;
    #pragma unroll 8
    for (int k = k0; k < k0 + 192; ++k)
      acc = fma4(sall[k], ld4(Wch + k * 256 + hq), acc);
    st4(&red[kg][hq], acc);
  }
  __syncthreads();
  if (kg == 0) {
    float4 r = add4(add4(ld4(&red[0][hq]), ld4(&red[1][hq])),
                    add4(ld4(&red[2][hq]), ld4(&red[3][hq])));
    r = relu4(add4(r, ld4(bch + hq)));
    st4(&sch[hq], r);
  }
  __syncthreads();

  {
    float4 f = make_float4(0.f, 0.f, 0.f, 0.f);
    const int k0 = kg * 64;
    #pragma unroll 8
    for (int k = k0; k < k0 + 64; ++k)
      f = fma4(sch[k], ld4(Wch2 + k * 256 + hq), f);
    const int s = t & 63;
    float sv = 0.f;
    if (s < 57) {
      #pragma unroll 8
      for (int k = k0; k < k0 + 64; ++k)
        sv = fmaf(sch[k], Wsem[k * 57 + s], sv);
    }
    redS[kg][s] = sv;
    __syncthreads();
    st4(&red[kg][hq], f);
  }
  __syncthreads();
  if (kg == 0) {
    float4 r = add4(add4(ld4(&red[0][hq]), ld4(&red[1][hq])),
                    add4(ld4(&red[2][hq]), ld4(&red[3][hq])));
    r = relu4(add4(r, ld4(bch2 + hq)));
    st4(&out_feats[m * 256 + hq], r);
    const int s = t & 63;
    if (s < 57)
      out_sem[m * 57 + s] = redS[0][s] + redS[1][s] + redS[2][s] + redS[3][s]
                          + bsem[s];
  }
}

// ---------------------------------------------------------------------------
extern "C" void kernel_launch(void* const* d_in, const int* in_sizes, int n_in,
                              void* d_out, int out_size, void* d_ws, size_t ws_size,
                              hipStream_t stream)
{
  const float* pf   = (const float*)d_in[0];
  const float* Wp   = (const float*)d_in[1];
  const float* bp   = (const float*)d_in[2];
  const float* Wex  = (const float*)d_in[3];
  const float* bex  = (const float*)d_in[4];
  const float* Wel  = (const float*)d_in[5];
  const float* bel  = (const float*)d_in[6];
  const float* Wee  = (const float*)d_in[7];
  const float* bee  = (const float*)d_in[8];
  const float* Wop  = (const float*)d_in[9];
  const float* bop  = (const float*)d_in[10];
  const float* Wch  = (const float*)d_in[11];
  const float* bch  = (const float*)d_in[12];
  const float* Wsem = (const float*)d_in[13];
  const float* bsem = (const float*)d_in[14];
  const float* Wch2 = (const float*)d_in[15];
  const float* bch2 = (const float*)d_in[16];

  // Output layout (fp32): feats | sem | exists | ee
  float* out_feats = (float*)d_out;
  float* out_sem   = out_feats + M_ * F_;
  float* out_ex    = out_sem + M_ * NSEM_;
  float* out_ee    = out_ex + M_;

  // Workspace (floats). part (1 MB) overlays part_op. Total ~19 MB.
  float* ws = (float*)d_ws;
  float* cf0 = ws;                     // 32768
  float* cf1 = ws + 32768;
  float* cf2 = ws + 65536;
  float* Ab  = ws + 98304;
  float* Bb  = ws + 131072;
  float* a1  = ws + 163840;
  float* a2  = ws + 196608;
  float* part    = ws + 229376;        // 262144 floats (dead after combine)
  float* part_op = ws + 229376;        // 131072 floats (overlay)
  unsigned short* W36F = (unsigned short*)(ws + 491520);  // 131072 bf16
  unsigned short* Cbuf = (unsigned short*)(ws + 557056);  // 8388608 bf16 (16.8 MB)

  k_parent_partial<<<256, 256, 0, stream>>>(pf, Wp, part);
  k_parent_combine<<<32, 256, 0, stream>>>(part, bp, cf0);
  k_ab<<<128, 256, 0, stream>>>(cf0, Wel, Wex, bex, Ab, Bb, out_ex);
  k_ee<<<512, 256, 0, stream>>>(Ab, Bb, bel, Wee, bee, out_ee);
  k_cvt_w<<<256, 256, 0, stream>>>(Wop, W36F);
  k_gemm<<<512, 512, 0, stream>>>(Ab, Bb, bel, W36F, Cbuf);

  float* cfs[3] = {cf0, cf1, cf2};
  for (int it = 0; it < 2; ++it) {
    const float* Wop_it = Wop + (size_t)it * 197632;
    const float* bop_it = bop + it * 256;
    k_a12<<<128, 256, 0, stream>>>(cfs[it], Wop_it, a1, a2);
    k_epi<<<512, 256, 0, stream>>>(Cbuf, it * 256, a1, a2, Wop_it, bop_it,
                                   out_ee, out_ex, part_op);
    k_op_combine<<<128, 256, 0, stream>>>(part_op, cfs[it + 1]);
  }
  k_final<<<128, 256, 0, stream>>>(cf0, cf1, cf2, Wch, bch, Wsem, bsem,
                                   Wch2, bch2, out_feats, out_sem);
}

// Round 4
// 89.509 us; speedup vs baseline: 2.9846x; 1.5435x over previous
//
#include <hip/hip_runtime.h>
#include <hip/hip_bf16.h>

// Shapes: M=128, H=256, F=256, T=4, I=2, NSEM=57
#define M_ 128
#define H_ 256
#define F_ 256
#define T_ 4
#define NSEM_ 57

typedef __attribute__((ext_vector_type(8))) short bf16x8;
typedef __attribute__((ext_vector_type(4))) float f32x4;

__device__ __forceinline__ float4 ld4(const float* p) { return *reinterpret_cast<const float4*>(p); }
__device__ __forceinline__ void st4(float* p, float4 v) { *reinterpret_cast<float4*>(p) = v; }
__device__ __forceinline__ float4 add4(float4 a, float4 b) { return make_float4(a.x+b.x, a.y+b.y, a.z+b.z, a.w+b.w); }
__device__ __forceinline__ float4 relu4(float4 a) { return make_float4(fmaxf(a.x,0.f), fmaxf(a.y,0.f), fmaxf(a.z,0.f), fmaxf(a.w,0.f)); }
__device__ __forceinline__ float4 fma4(float s, float4 w, float4 c) { return make_float4(fmaf(s,w.x,c.x), fmaf(s,w.y,c.y), fmaf(s,w.z,c.z), fmaf(s,w.w,c.w)); }

__device__ __forceinline__ unsigned short f2bfu(float x) {
  unsigned u = __float_as_uint(x);
  return (unsigned short)((u + 0x7FFFu + ((u >> 16) & 1u)) >> 16);  // RNE
}
__device__ __forceinline__ float bfu2f(unsigned short b) {
  return __uint_as_float(((unsigned)b) << 16);
}
__device__ __forceinline__ unsigned pack2(float lo, float hi) {
  return (unsigned)f2bfu(lo) | ((unsigned)f2bfu(hi) << 16);
}

// ---------------------------------------------------------------------------
// K1: partial parent matmul. grid 512 = 32 col-blocks x 16 k-chunks, 256 thr.
// 2 blocks/CU, 16 independent dwordx4 streams per thread. 33.5 MB read.
// ---------------------------------------------------------------------------
__global__ void __launch_bounds__(256) k_parent_partial(
    const float* __restrict__ pf, const float* __restrict__ Wp,
    float* __restrict__ part)
{
  const int cb = (blockIdx.x & 31) * 1024 + threadIdx.x * 4;
  const int kc = blockIdx.x >> 5;
  __shared__ float spf[16];
  if (threadIdx.x < 16) spf[threadIdx.x] = pf[kc * 16 + threadIdx.x];
  __syncthreads();
  const float* w = Wp + (size_t)kc * 16 * 32768 + cb;
  float4 acc = make_float4(0.f, 0.f, 0.f, 0.f);
  #pragma unroll
  for (int k = 0; k < 16; ++k)
    acc = fma4(spf[k], ld4(w + (size_t)k * 32768), acc);
  st4(&part[kc * 32768 + cb], acc);
}

// ---------------------------------------------------------------------------
// K_stage1: fused parent_combine + A/B + a1/a2(it0) + exists.
// grid 256 = (m, sel), 256 thr. sel=0: {A, a1_0, cf0 store, exists};
// sel=1: {B, a2_0}. K=256 split across 4 waves, float4 cols, LDS reduce.
// ---------------------------------------------------------------------------
__global__ void __launch_bounds__(256) k_stage1(
    const float* __restrict__ part, const float* __restrict__ bp,
    const float* __restrict__ Wel, const float* __restrict__ Wop0,
    const float* __restrict__ Wex, const float* __restrict__ bex,
    float* __restrict__ cf0, float* __restrict__ A, float* __restrict__ B,
    float* __restrict__ a1, float* __restrict__ a2,
    float* __restrict__ out_ex)
{
  const int m = blockIdx.x >> 1, sel = blockIdx.x & 1;
  const int t = threadIdx.x;
  __shared__ float sall[256];
  __shared__ float red[2][4][256];
  __shared__ float redE[4];

  // head: combine 16 partials + bias + relu -> cf0 row
  float v = bp[m * 256 + t];
  #pragma unroll
  for (int q = 0; q < 16; ++q) v += part[q * 32768 + m * 256 + t];
  v = fmaxf(v, 0.f);
  sall[t] = v;
  if (sel == 0) {
    cf0[m * 256 + t] = v;
    float p = v * Wex[t];
    #pragma unroll
    for (int off = 32; off > 0; off >>= 1) p += __shfl_xor(p, off);
    if ((t & 63) == 0) redE[t >> 6] = p;
  }
  __syncthreads();

  // GEMV: 2 weight streams for this sel
  const float* W0 = Wel  + (sel ? 65536 : 0);   // -> A (sel0) / B (sel1)
  const float* W1 = Wop0 + (sel ? 65536 : 0);   // -> a1 (sel0) / a2 (sel1)
  const int hq = (t & 63) << 2, kg = t >> 6, k0 = kg * 64;
  float4 acc0 = make_float4(0.f, 0.f, 0.f, 0.f), acc1 = acc0;
  #pragma unroll 4
  for (int k = k0; k < k0 + 64; ++k) {
    const float s = sall[k];
    acc0 = fma4(s, ld4(W0 + k * 256 + hq), acc0);
    acc1 = fma4(s, ld4(W1 + k * 256 + hq), acc1);
  }
  st4(&red[0][kg][hq], acc0);
  st4(&red[1][kg][hq], acc1);
  __syncthreads();
  if (kg < 2) {
    float4 r = add4(add4(ld4(&red[kg][0][hq]), ld4(&red[kg][1][hq])),
                    add4(ld4(&red[kg][2][hq]), ld4(&red[kg][3][hq])));
    float* dst = (kg == 0) ? (sel ? B : A) : (sel ? a2 : a1);
    st4(&dst[m * 256 + hq], r);
  }
  if (sel == 0 && t == 0)
    out_ex[m] = redE[0] + redE[1] + redE[2] + redE[3] + bex[0];
}

// ---------------------------------------------------------------------------
// K3: ee fp32 exact (mask depends on sign). grid 512 = (i, j-quarter).
// ---------------------------------------------------------------------------
__global__ void __launch_bounds__(256) k_ee(
    const float* __restrict__ A, const float* __restrict__ B,
    const float* __restrict__ bel, const float* __restrict__ Wee,
    const float* __restrict__ bee, float* __restrict__ out_ee)
{
  const int i = blockIdx.x >> 2, jq = blockIdx.x & 3;
  const int w = threadIdx.x >> 6, l = threadIdx.x & 63;
  float a[4], bl[4], we0[4], we1[4], we2[4], we3[4];
  #pragma unroll
  for (int q = 0; q < 4; ++q) {
    a[q]  = A[i * 256 + q * 64 + l];
    bl[q] = bel[q * 64 + l];
    we0[q] = Wee[0 * 256 + q * 64 + l];
    we1[q] = Wee[1 * 256 + q * 64 + l];
    we2[q] = Wee[2 * 256 + q * 64 + l];
    we3[q] = Wee[3 * 256 + q * 64 + l];
  }
  const float be0 = bee[0], be1 = bee[1], be2 = bee[2], be3 = bee[3];
  for (int jj = 0; jj < 8; ++jj) {
    const int j = jq * 32 + w + jj * 4;
    float s0 = 0.f, s1 = 0.f, s2 = 0.f, s3 = 0.f;
    #pragma unroll
    for (int q = 0; q < 4; ++q) {
      const float e = fmaxf(a[q] + bl[q] + B[j * 256 + q * 64 + l], 0.f);
      s0 = fmaf(e, we0[q], s0);
      s1 = fmaf(e, we1[q], s1);
      s2 = fmaf(e, we2[q], s2);
      s3 = fmaf(e, we3[q], s3);
    }
    for (int off = 32; off > 0; off >>= 1) {
      s0 += __shfl_xor(s0, off);
      s1 += __shfl_xor(s1, off);
      s2 += __shfl_xor(s2, off);
      s3 += __shfl_xor(s3, off);
    }
    if (l < 4) {
      const float v = (l == 0) ? (s0 + be0) : (l == 1) ? (s1 + be1)
                     : (l == 2) ? (s2 + be2) : (s3 + be3);
      out_ee[(i * 128 + j) * 4 + l] = v;
    }
  }
}

// ---------------------------------------------------------------------------
// K_cvt: pack W3 of both iterations into MFMA-b-frag-ordered bf16.
// ---------------------------------------------------------------------------
__global__ void __launch_bounds__(256) k_cvt_w(
    const float* __restrict__ Wop, unsigned short* __restrict__ W36F)
{
  const int fb = blockIdx.x;
  const int ct = fb >> 3, kc = fb & 7;
  #pragma unroll
  for (int r = 0; r < 2; ++r) {
    const int e = threadIdx.x * 2 + r;
    const int l = e >> 3, q = e & 7;
    const int c = ct * 16 + (l & 15);
    const int k = kc * 32 + (l >> 4) * 8 + q;
    const int it = c >> 8, h = c & 255;
    W36F[fb * 512 + e] = f2bfu(Wop[(size_t)it * 197632 + (512 + k) * 256 + h]);
  }
}

// ---------------------------------------------------------------------------
// K_gemm: C[i,j,0:512] = EL_i[j,:] @ [W3_0 | W3_1]  (bf16 MFMA, fp32 acc).
// grid 512 = (i, j-quarter), 512 thr = 8 waves. XOR-swizzled LDS EL tile.
// ---------------------------------------------------------------------------
__global__ void __launch_bounds__(512) k_gemm(
    const float* __restrict__ Arow, const float* __restrict__ Brow,
    const float* __restrict__ bel, const unsigned short* __restrict__ W36F,
    unsigned short* __restrict__ C)
{
  const int i  = blockIdx.x >> 2;
  const int jq = blockIdx.x & 3;
  const int t  = threadIdx.x;
  const int w  = t >> 6;
  const int l  = t & 63;
  __shared__ char sEL[32 * 512];

  {
    const int row = t >> 4;
    const int kb  = (t & 15) * 16;
    const float* Ap  = Arow + i * 256 + kb;
    const float* Bp  = Brow + (jq * 32 + row) * 256 + kb;
    const float* blp = bel + kb;
    float e[16];
    #pragma unroll
    for (int q = 0; q < 16; q += 4) {
      float4 av = ld4(Ap + q), bv = ld4(Bp + q), lv = ld4(blp + q);
      e[q+0] = fmaxf(av.x + bv.x + lv.x, 0.f);
      e[q+1] = fmaxf(av.y + bv.y + lv.y, 0.f);
      e[q+2] = fmaxf(av.z + bv.z + lv.z, 0.f);
      e[q+3] = fmaxf(av.w + bv.w + lv.w, 0.f);
    }
    const int swz = (row & 7) << 4;
    uint4 w0, w1;
    w0.x = pack2(e[0], e[1]);  w0.y = pack2(e[2], e[3]);
    w0.z = pack2(e[4], e[5]);  w0.w = pack2(e[6], e[7]);
    w1.x = pack2(e[8], e[9]);  w1.y = pack2(e[10], e[11]);
    w1.z = pack2(e[12], e[13]); w1.w = pack2(e[14], e[15]);
    *reinterpret_cast<uint4*>(sEL + ((row * 512 + kb * 2)      ^ swz)) = w0;
    *reinterpret_cast<uint4*>(sEL + ((row * 512 + kb * 2 + 16) ^ swz)) = w1;
  }
  __syncthreads();

  const int lr = l & 15, lk = l >> 4;
  f32x4 acc[2][4];
  #pragma unroll
  for (int jt = 0; jt < 2; ++jt)
    #pragma unroll
    for (int ct = 0; ct < 4; ++ct)
      acc[jt][ct] = (f32x4){0.f, 0.f, 0.f, 0.f};

  for (int kc = 0; kc < 8; ++kc) {
    const int r0 = lr, r1 = 16 + lr;
    const int kbyte = kc * 64 + lk * 16;
    bf16x8 af0 = *reinterpret_cast<const bf16x8*>(
        sEL + ((r0 * 512 + kbyte) ^ ((r0 & 7) << 4)));
    bf16x8 af1 = *reinterpret_cast<const bf16x8*>(
        sEL + ((r1 * 512 + kbyte) ^ ((r1 & 7) << 4)));
    #pragma unroll
    for (int ct = 0; ct < 4; ++ct) {
      const int fb = (w * 4 + ct) * 8 + kc;
      bf16x8 bf = *reinterpret_cast<const bf16x8*>(W36F + fb * 512 + l * 8);
      acc[0][ct] = __builtin_amdgcn_mfma_f32_16x16x32_bf16(af0, bf, acc[0][ct], 0, 0, 0);
      acc[1][ct] = __builtin_amdgcn_mfma_f32_16x16x32_bf16(af1, bf, acc[1][ct], 0, 0, 0);
    }
  }

  #pragma unroll
  for (int jt = 0; jt < 2; ++jt) {
    #pragma unroll
    for (int ct = 0; ct < 4; ++ct) {
      const int c = w * 64 + ct * 16 + lr;
      #pragma unroll
      for (int q = 0; q < 4; ++q) {
        const int j = jq * 32 + jt * 16 + lk * 4 + q;
        C[(size_t)(i * 128 + j) * 512 + c] = f2bfu(acc[jt][ct][q]);
      }
    }
  }
}

// ---------------------------------------------------------------------------
// K_epi: masked relu-max epilogue per iteration. grid 512 = (i, jq), 256 thr.
// ---------------------------------------------------------------------------
__global__ void __launch_bounds__(256) k_epi(
    const unsigned short* __restrict__ C, const int itoff,
    const float* __restrict__ a1, const float* __restrict__ a2,
    const float* __restrict__ Wop_it, const float* __restrict__ bop_it,
    const float* __restrict__ ee, const float* __restrict__ exlog,
    float* __restrict__ part_op)
{
  const int i = blockIdx.x >> 2, jq = blockIdx.x & 3;
  const int h = threadIdx.x;
  const float base1 = a1[i * 256 + h] + bop_it[h];
  const float w40 = Wop_it[(768 + 0) * 256 + h];
  const float w41 = Wop_it[(768 + 1) * 256 + h];
  const float w42 = Wop_it[(768 + 2) * 256 + h];
  const float w43 = Wop_it[(768 + 3) * 256 + h];
  float acc = 0.f;
  if (exlog[i] > 0.f) {
    #pragma unroll 4
    for (int jj = 0; jj < 32; ++jj) {
      const int j = jq * 32 + jj;
      if (exlog[j] > 0.f) {
        const float cv = bfu2f(C[(size_t)(i * 128 + j) * 512 + itoff + h]);
        const float pb = base1 + a2[j * 256 + h] + cv;
        const float e0 = ee[(i * 128 + j) * 4 + 0];
        const float e1 = ee[(i * 128 + j) * 4 + 1];
        const float e2 = ee[(i * 128 + j) * 4 + 2];
        const float e3 = ee[(i * 128 + j) * 4 + 3];
        if (e0 > 0.f) acc = fmaxf(acc, fmaxf(fmaf(e0, w40, pb), 0.f));
        if (e1 > 0.f) acc = fmaxf(acc, fmaxf(fmaf(e1, w41, pb), 0.f));
        if (e2 > 0.f) acc = fmaxf(acc, fmaxf(fmaf(e2, w42, pb), 0.f));
        if (e3 > 0.f) acc = fmaxf(acc, fmaxf(fmaf(e3, w43, pb), 0.f));
      }
    }
  }
  part_op[(i * 4 + jq) * 256 + h] = acc;
}

// ---------------------------------------------------------------------------
// K_a12b: fused op_combine(it0) + a1/a2(it1). grid 256 = (m, sel), 256 thr.
// ---------------------------------------------------------------------------
__global__ void __launch_bounds__(256) k_a12b(
    const float* __restrict__ part_op, const float* __restrict__ Wop1,
    float* __restrict__ cf1, float* __restrict__ a1, float* __restrict__ a2)
{
  const int m = blockIdx.x >> 1, sel = blockIdx.x & 1;
  const int t = threadIdx.x;
  __shared__ float sall[256];
  __shared__ float red[4][256];
  float v = part_op[(m * 4 + 0) * 256 + t];
  v = fmaxf(v, part_op[(m * 4 + 1) * 256 + t]);
  v = fmaxf(v, part_op[(m * 4 + 2) * 256 + t]);
  v = fmaxf(v, part_op[(m * 4 + 3) * 256 + t]);
  sall[t] = v;
  if (sel == 0) cf1[m * 256 + t] = v;
  __syncthreads();
  const float* W = Wop1 + (sel ? 65536 : 0);
  const int hq = (t & 63) << 2, kg = t >> 6, k0 = kg * 64;
  float4 acc = make_float4(0.f, 0.f, 0.f, 0.f);
  #pragma unroll 4
  for (int k = k0; k < k0 + 64; ++k)
    acc = fma4(sall[k], ld4(W + k * 256 + hq), acc);
  st4(&red[kg][hq], acc);
  __syncthreads();
  if (kg == 0) {
    float4 r = add4(add4(ld4(&red[0][hq]), ld4(&red[1][hq])),
                    add4(ld4(&red[2][hq]), ld4(&red[3][hq])));
    st4(&((sel ? a2 : a1)[m * 256 + hq]), r);
  }
}

// ---------------------------------------------------------------------------
// K5: ch/sem/feats; cf2 combined inline from part_op (it1).
// ---------------------------------------------------------------------------
__global__ void __launch_bounds__(256) k_final(
    const float* __restrict__ cf0, const float* __restrict__ cf1,
    const float* __restrict__ part_op,
    const float* __restrict__ Wch, const float* __restrict__ bch,
    const float* __restrict__ Wsem, const float* __restrict__ bsem,
    const float* __restrict__ Wch2, const float* __restrict__ bch2,
    float* __restrict__ out_feats, float* __restrict__ out_sem)
{
  const int m  = blockIdx.x;
  const int t  = threadIdx.x;
  const int hq = (t & 63) << 2;
  const int kg = t >> 6;
  __shared__ float sall[768];
  __shared__ float sch[256];
  __shared__ float red[4][256];
  __shared__ float redS[4][64];

  sall[t]       = cf0[m * 256 + t];
  sall[256 + t] = cf1[m * 256 + t];
  {
    float v = part_op[(m * 4 + 0) * 256 + t];
    v = fmaxf(v, part_op[(m * 4 + 1) * 256 + t]);
    v = fmaxf(v, part_op[(m * 4 + 2) * 256 + t]);
    v = fmaxf(v, part_op[(m * 4 + 3) * 256 + t]);
    sall[512 + t] = v;
  }
  __syncthreads();

  {
    float4 acc = make_float4(0.f, 0.f, 0.f, 0.f);
    const int k0 = kg * 192;
    #pragma unroll 8
    for (int k = k0; k < k0 + 192; ++k)
      acc = fma4(sall[k], ld4(Wch + k * 256 + hq), acc);
    st4(&red[kg][hq], acc);
  }
  __syncthreads();
  if (kg == 0) {
    float4 r = add4(add4(ld4(&red[0][hq]), ld4(&red[1][hq])),
                    add4(ld4(&red[2][hq]), ld4(&red[3][hq])));
    r = relu4(add4(r, ld4(bch + hq)));
    st4(&sch[hq], r);
  }
  __syncthreads();

  {
    float4 f = make_float4(0.f, 0.f, 0.f, 0.f);
    const int k0 = kg * 64;
    #pragma unroll 8
    for (int k = k0; k < k0 + 64; ++k)
      f = fma4(sch[k], ld4(Wch2 + k * 256 + hq), f);
    const int s = t & 63;
    float sv = 0.f;
    if (s < 57) {
      #pragma unroll 8
      for (int k = k0; k < k0 + 64; ++k)
        sv = fmaf(sch[k], Wsem[k * 57 + s], sv);
    }
    redS[kg][s] = sv;
    __syncthreads();
    st4(&red[kg][hq], f);
  }
  __syncthreads();
  if (kg == 0) {
    float4 r = add4(add4(ld4(&red[0][hq]), ld4(&red[1][hq])),
                    add4(ld4(&red[2][hq]), ld4(&red[3][hq])));
    r = relu4(add4(r, ld4(bch2 + hq)));
    st4(&out_feats[m * 256 + hq], r);
    const int s = t & 63;
    if (s < 57)
      out_sem[m * 57 + s] = redS[0][s] + redS[1][s] + redS[2][s] + redS[3][s]
                          + bsem[s];
  }
}

// ---------------------------------------------------------------------------
extern "C" void kernel_launch(void* const* d_in, const int* in_sizes, int n_in,
                              void* d_out, int out_size, void* d_ws, size_t ws_size,
                              hipStream_t stream)
{
  const float* pf   = (const float*)d_in[0];
  const float* Wp   = (const float*)d_in[1];
  const float* bp   = (const float*)d_in[2];
  const float* Wex  = (const float*)d_in[3];
  const float* bex  = (const float*)d_in[4];
  const float* Wel  = (const float*)d_in[5];
  const float* bel  = (const float*)d_in[6];
  const float* Wee  = (const float*)d_in[7];
  const float* bee  = (const float*)d_in[8];
  const float* Wop  = (const float*)d_in[9];
  const float* bop  = (const float*)d_in[10];
  const float* Wch  = (const float*)d_in[11];
  const float* bch  = (const float*)d_in[12];
  const float* Wsem = (const float*)d_in[13];
  const float* bsem = (const float*)d_in[14];
  const float* Wch2 = (const float*)d_in[15];
  const float* bch2 = (const float*)d_in[16];

  // Output layout (fp32): feats | sem | exists | ee
  float* out_feats = (float*)d_out;
  float* out_sem   = out_feats + M_ * F_;
  float* out_ex    = out_sem + M_ * NSEM_;
  float* out_ee    = out_ex + M_;

  // Workspace (floats). part (2 MB, 16 chunks) overlays part_op.
  float* ws = (float*)d_ws;
  float* cf0 = ws;                     // 32768
  float* cf1 = ws + 32768;             // 32768
  float* Ab  = ws + 65536;             // 32768
  float* Bb  = ws + 98304;             // 32768
  float* a1  = ws + 131072;            // 32768
  float* a2  = ws + 163840;            // 32768
  float* part    = ws + 196608;        // 524288 (dead after stage1)
  float* part_op = ws + 196608;        // 131072 (overlay)
  unsigned short* W36F = (unsigned short*)(ws + 720896);  // 131072 bf16
  unsigned short* Cbuf = (unsigned short*)(ws + 786432);  // 8388608 bf16

  const float* Wop0 = Wop;               // iteration 0 block (772*256 floats)
  const float* Wop1 = Wop + 197632;      // iteration 1 block

  k_parent_partial<<<512, 256, 0, stream>>>(pf, Wp, part);
  k_stage1<<<256, 256, 0, stream>>>(part, bp, Wel, Wop0, Wex, bex,
                                    cf0, Ab, Bb, a1, a2, out_ex);
  k_ee<<<512, 256, 0, stream>>>(Ab, Bb, bel, Wee, bee, out_ee);
  k_cvt_w<<<256, 256, 0, stream>>>(Wop, W36F);
  k_gemm<<<512, 512, 0, stream>>>(Ab, Bb, bel, W36F, Cbuf);

  k_epi<<<512, 256, 0, stream>>>(Cbuf, 0, a1, a2, Wop0, bop,
                                 out_ee, out_ex, part_op);
  k_a12b<<<256, 256, 0, stream>>>(part_op, Wop1, cf1, a1, a2);
  k_epi<<<512, 256, 0, stream>>>(Cbuf, 256, a1, a2, Wop1, bop + 256,
                                 out_ee, out_ex, part_op);
  k_final<<<128, 256, 0, stream>>>(cf0, cf1, part_op, Wch, bch, Wsem, bsem,
                                   Wch2, bch2, out_feats, out_sem);
}

// Round 5
// 71.120 us; speedup vs baseline: 3.7563x; 1.2586x over previous
//
#include <hip/hip_runtime.h>
#include <hip/hip_bf16.h>

// Shapes: M=128, H=256, F=256, T=4, I=2, NSEM=57
#define M_ 128
#define H_ 256
#define F_ 256
#define T_ 4
#define NSEM_ 57

typedef __attribute__((ext_vector_type(8))) short bf16x8;
typedef __attribute__((ext_vector_type(4))) float f32x4;

__device__ __forceinline__ float4 ld4(const float* p) { return *reinterpret_cast<const float4*>(p); }
__device__ __forceinline__ void st4(float* p, float4 v) { *reinterpret_cast<float4*>(p) = v; }
__device__ __forceinline__ float4 add4(float4 a, float4 b) { return make_float4(a.x+b.x, a.y+b.y, a.z+b.z, a.w+b.w); }
__device__ __forceinline__ float4 relu4(float4 a) { return make_float4(fmaxf(a.x,0.f), fmaxf(a.y,0.f), fmaxf(a.z,0.f), fmaxf(a.w,0.f)); }
__device__ __forceinline__ float4 fma4(float s, float4 w, float4 c) { return make_float4(fmaf(s,w.x,c.x), fmaf(s,w.y,c.y), fmaf(s,w.z,c.z), fmaf(s,w.w,c.w)); }

__device__ __forceinline__ unsigned short f2bfu(float x) {
  unsigned u = __float_as_uint(x);
  return (unsigned short)((u + 0x7FFFu + ((u >> 16) & 1u)) >> 16);  // RNE
}
__device__ __forceinline__ unsigned pack2(float lo, float hi) {
  return (unsigned)f2bfu(lo) | ((unsigned)f2bfu(hi) << 16);
}

// ---------------------------------------------------------------------------
// K1: partial parent matmul. grid 512 = 32 col-blocks x 16 k-chunks, 256 thr.
// ---------------------------------------------------------------------------
__global__ void __launch_bounds__(256) k_parent_partial(
    const float* __restrict__ pf, const float* __restrict__ Wp,
    float* __restrict__ part)
{
  const int cb = (blockIdx.x & 31) * 1024 + threadIdx.x * 4;
  const int kc = blockIdx.x >> 5;
  __shared__ float spf[16];
  if (threadIdx.x < 16) spf[threadIdx.x] = pf[kc * 16 + threadIdx.x];
  __syncthreads();
  const float* w = Wp + (size_t)kc * 16 * 32768 + cb;
  float4 acc = make_float4(0.f, 0.f, 0.f, 0.f);
  #pragma unroll
  for (int k = 0; k < 16; ++k)
    acc = fma4(spf[k], ld4(w + (size_t)k * 32768), acc);
  st4(&part[kc * 32768 + cb], acc);
}

// ---------------------------------------------------------------------------
// K_stage1: fused parent_combine + A/B + a1/a2(it0) + exists.
// grid 256 = (m, sel), 256 thr.
// ---------------------------------------------------------------------------
__global__ void __launch_bounds__(256) k_stage1(
    const float* __restrict__ part, const float* __restrict__ bp,
    const float* __restrict__ Wel, const float* __restrict__ Wop0,
    const float* __restrict__ Wex, const float* __restrict__ bex,
    float* __restrict__ cf0, float* __restrict__ A, float* __restrict__ B,
    float* __restrict__ a1, float* __restrict__ a2,
    float* __restrict__ out_ex)
{
  const int m = blockIdx.x >> 1, sel = blockIdx.x & 1;
  const int t = threadIdx.x;
  __shared__ float sall[256];
  __shared__ float red[2][4][256];
  __shared__ float redE[4];

  float v = bp[m * 256 + t];
  #pragma unroll
  for (int q = 0; q < 16; ++q) v += part[q * 32768 + m * 256 + t];
  v = fmaxf(v, 0.f);
  sall[t] = v;
  if (sel == 0) {
    cf0[m * 256 + t] = v;
    float p = v * Wex[t];
    #pragma unroll
    for (int off = 32; off > 0; off >>= 1) p += __shfl_xor(p, off);
    if ((t & 63) == 0) redE[t >> 6] = p;
  }
  __syncthreads();

  const float* W0 = Wel  + (sel ? 65536 : 0);
  const float* W1 = Wop0 + (sel ? 65536 : 0);
  const int hq = (t & 63) << 2, kg = t >> 6, k0 = kg * 64;
  float4 acc0 = make_float4(0.f, 0.f, 0.f, 0.f), acc1 = acc0;
  #pragma unroll 4
  for (int k = k0; k < k0 + 64; ++k) {
    const float s = sall[k];
    acc0 = fma4(s, ld4(W0 + k * 256 + hq), acc0);
    acc1 = fma4(s, ld4(W1 + k * 256 + hq), acc1);
  }
  st4(&red[0][kg][hq], acc0);
  st4(&red[1][kg][hq], acc1);
  __syncthreads();
  if (kg < 2) {
    float4 r = add4(add4(ld4(&red[kg][0][hq]), ld4(&red[kg][1][hq])),
                    add4(ld4(&red[kg][2][hq]), ld4(&red[kg][3][hq])));
    float* dst = (kg == 0) ? (sel ? B : A) : (sel ? a2 : a1);
    st4(&dst[m * 256 + hq], r);
  }
  if (sel == 0 && t == 0)
    out_ex[m] = redE[0] + redE[1] + redE[2] + redE[3] + bex[0];
}

// ---------------------------------------------------------------------------
// K_cvt: pack W3 of both iterations into MFMA-b-frag-ordered bf16.
// ---------------------------------------------------------------------------
__global__ void __launch_bounds__(256) k_cvt_w(
    const float* __restrict__ Wop, unsigned short* __restrict__ W36F)
{
  const int fb = blockIdx.x;
  const int ct = fb >> 3, kc = fb & 7;
  #pragma unroll
  for (int r = 0; r < 2; ++r) {
    const int e = threadIdx.x * 2 + r;
    const int l = e >> 3, q = e & 7;
    const int c = ct * 16 + (l & 15);
    const int k = kc * 32 + (l >> 4) * 8 + q;
    const int it = c >> 8, h = c & 255;
    W36F[fb * 512 + e] = f2bfu(Wop[(size_t)it * 197632 + (512 + k) * 256 + h]);
  }
}

// ---------------------------------------------------------------------------
// K_gemm_epi<IT>: per (i, jq) block: recompute EL tile (fp32), (IT==0) compute
// ee via in-block dot + 16-lane shfl reduce and write out_ee; pack EL bf16
// into XOR-swizzled LDS; MFMA against W3_IT frags (8 waves x 32 cols);
// fused masked relu-max epilogue in fp32 -> part_op. No C buffer at all.
// ---------------------------------------------------------------------------
template<int IT>
__global__ void __launch_bounds__(512) k_gemm_epi(
    const float* __restrict__ Arow, const float* __restrict__ Brow,
    const float* __restrict__ bel, const unsigned short* __restrict__ W36F,
    const float* __restrict__ Wee, const float* __restrict__ bee,
    const float* __restrict__ a1, const float* __restrict__ a2,
    const float* __restrict__ Wop_it, const float* __restrict__ bop_it,
    const float* __restrict__ exlog,
    float* __restrict__ ee_g,          // written (IT=0) / read (IT=1)
    float* __restrict__ part_op)
{
  const int i  = blockIdx.x >> 2;
  const int jq = blockIdx.x & 3;
  const int t  = threadIdx.x;
  const int w  = t >> 6;
  const int l  = t & 63;
  __shared__ char sEL[32 * 512];
  __shared__ float see[32][4];
  __shared__ float sexf[32];

  const bool exi = exlog[i] > 0.f;

  // ---- stage EL tile (fp32) + pack bf16 + (IT0) ee
  {
    const int row = t >> 4;        // 0..31
    const int sub = t & 15;
    const int kb  = sub * 16;
    const float* Ap  = Arow + i * 256 + kb;
    const float* Bp  = Brow + (jq * 32 + row) * 256 + kb;
    const float* blp = bel + kb;
    float e[16];
    #pragma unroll
    for (int q = 0; q < 16; q += 4) {
      float4 av = ld4(Ap + q), bv = ld4(Bp + q), lv = ld4(blp + q);
      e[q+0] = fmaxf(av.x + bv.x + lv.x, 0.f);
      e[q+1] = fmaxf(av.y + bv.y + lv.y, 0.f);
      e[q+2] = fmaxf(av.z + bv.z + lv.z, 0.f);
      e[q+3] = fmaxf(av.w + bv.w + lv.w, 0.f);
    }
    if (IT == 0) {
      float s[4] = {0.f, 0.f, 0.f, 0.f};
      #pragma unroll
      for (int tt = 0; tt < 4; ++tt) {
        #pragma unroll
        for (int q = 0; q < 16; q += 4) {
          float4 wv = ld4(Wee + tt * 256 + kb + q);
          s[tt] = fmaf(e[q+0], wv.x, s[tt]);
          s[tt] = fmaf(e[q+1], wv.y, s[tt]);
          s[tt] = fmaf(e[q+2], wv.z, s[tt]);
          s[tt] = fmaf(e[q+3], wv.w, s[tt]);
        }
      }
      #pragma unroll
      for (int off = 1; off < 16; off <<= 1) {
        s[0] += __shfl_xor(s[0], off);
        s[1] += __shfl_xor(s[1], off);
        s[2] += __shfl_xor(s[2], off);
        s[3] += __shfl_xor(s[3], off);
      }
      if (sub < 4) {
        const float v = s[sub] + bee[sub];
        see[row][sub] = v;
        ee_g[(i * 128 + jq * 32 + row) * 4 + sub] = v;
      }
    }
    const int swz = (row & 7) << 4;
    uint4 w0, w1;
    w0.x = pack2(e[0], e[1]);  w0.y = pack2(e[2], e[3]);
    w0.z = pack2(e[4], e[5]);  w0.w = pack2(e[6], e[7]);
    w1.x = pack2(e[8], e[9]);  w1.y = pack2(e[10], e[11]);
    w1.z = pack2(e[12], e[13]); w1.w = pack2(e[14], e[15]);
    *reinterpret_cast<uint4*>(sEL + ((row * 512 + kb * 2)      ^ swz)) = w0;
    *reinterpret_cast<uint4*>(sEL + ((row * 512 + kb * 2 + 16) ^ swz)) = w1;
  }
  if (IT == 1) {
    if (t < 128) see[t >> 2][t & 3] = ee_g[(i * 128 + jq * 32 + (t >> 2)) * 4 + (t & 3)];
  }
  if (t < 32) sexf[t] = exlog[jq * 32 + t];
  __syncthreads();

  // ---- MFMA: wave w owns cols [w*32, w*32+32) of this iteration's 256
  const int lr = l & 15, lk = l >> 4;
  f32x4 acc[2][2];
  #pragma unroll
  for (int jt = 0; jt < 2; ++jt)
    #pragma unroll
    for (int ct = 0; ct < 2; ++ct)
      acc[jt][ct] = (f32x4){0.f, 0.f, 0.f, 0.f};

  for (int kc = 0; kc < 8; ++kc) {
    const int r0 = lr, r1 = 16 + lr;
    const int kbyte = kc * 64 + lk * 16;
    bf16x8 af0 = *reinterpret_cast<const bf16x8*>(
        sEL + ((r0 * 512 + kbyte) ^ ((r0 & 7) << 4)));
    bf16x8 af1 = *reinterpret_cast<const bf16x8*>(
        sEL + ((r1 * 512 + kbyte) ^ ((r1 & 7) << 4)));
    #pragma unroll
    for (int ct = 0; ct < 2; ++ct) {
      const int fb = (IT * 16 + w * 2 + ct) * 8 + kc;
      bf16x8 bf = *reinterpret_cast<const bf16x8*>(W36F + fb * 512 + l * 8);
      acc[0][ct] = __builtin_amdgcn_mfma_f32_16x16x32_bf16(af0, bf, acc[0][ct], 0, 0, 0);
      acc[1][ct] = __builtin_amdgcn_mfma_f32_16x16x32_bf16(af1, bf, acc[1][ct], 0, 0, 0);
    }
  }

  // ---- fused epilogue (fp32 acc, no C round-trip)
  const int c0 = w * 32 + lr, c1 = c0 + 16;
  const float b10 = a1[i * 256 + c0] + bop_it[c0];
  const float b11 = a1[i * 256 + c1] + bop_it[c1];
  float w40[4], w41[4];
  #pragma unroll
  for (int tt = 0; tt < 4; ++tt) {
    w40[tt] = Wop_it[(768 + tt) * 256 + c0];
    w41[tt] = Wop_it[(768 + tt) * 256 + c1];
  }
  float am0 = 0.f, am1 = 0.f;
  #pragma unroll
  for (int jt = 0; jt < 2; ++jt) {
    #pragma unroll
    for (int q = 0; q < 4; ++q) {
      const int jrow = jt * 16 + lk * 4 + q;
      const int j = jq * 32 + jrow;
      if (exi && (sexf[jrow] > 0.f)) {
        const float e0 = see[jrow][0], e1 = see[jrow][1];
        const float e2 = see[jrow][2], e3 = see[jrow][3];
        const float pb0 = b10 + a2[j * 256 + c0] + acc[jt][0][q];
        const float pb1 = b11 + a2[j * 256 + c1] + acc[jt][1][q];
        if (e0 > 0.f) { am0 = fmaxf(am0, fmaxf(fmaf(e0, w40[0], pb0), 0.f));
                        am1 = fmaxf(am1, fmaxf(fmaf(e0, w41[0], pb1), 0.f)); }
        if (e1 > 0.f) { am0 = fmaxf(am0, fmaxf(fmaf(e1, w40[1], pb0), 0.f));
                        am1 = fmaxf(am1, fmaxf(fmaf(e1, w41[1], pb1), 0.f)); }
        if (e2 > 0.f) { am0 = fmaxf(am0, fmaxf(fmaf(e2, w40[2], pb0), 0.f));
                        am1 = fmaxf(am1, fmaxf(fmaf(e2, w41[2], pb1), 0.f)); }
        if (e3 > 0.f) { am0 = fmaxf(am0, fmaxf(fmaf(e3, w40[3], pb0), 0.f));
                        am1 = fmaxf(am1, fmaxf(fmaf(e3, w41[3], pb1), 0.f)); }
      }
    }
  }
  am0 = fmaxf(am0, __shfl_xor(am0, 16));
  am0 = fmaxf(am0, __shfl_xor(am0, 32));
  am1 = fmaxf(am1, __shfl_xor(am1, 16));
  am1 = fmaxf(am1, __shfl_xor(am1, 32));
  if (lk == 0) {
    part_op[(i * 4 + jq) * 256 + c0] = am0;
    part_op[(i * 4 + jq) * 256 + c1] = am1;
  }
}

// ---------------------------------------------------------------------------
// K_a12b: fused op_combine(it0) + a1/a2(it1). grid 256 = (m, sel), 256 thr.
// ---------------------------------------------------------------------------
__global__ void __launch_bounds__(256) k_a12b(
    const float* __restrict__ part_op, const float* __restrict__ Wop1,
    float* __restrict__ cf1, float* __restrict__ a1, float* __restrict__ a2)
{
  const int m = blockIdx.x >> 1, sel = blockIdx.x & 1;
  const int t = threadIdx.x;
  __shared__ float sall[256];
  __shared__ float red[4][256];
  float v = part_op[(m * 4 + 0) * 256 + t];
  v = fmaxf(v, part_op[(m * 4 + 1) * 256 + t]);
  v = fmaxf(v, part_op[(m * 4 + 2) * 256 + t]);
  v = fmaxf(v, part_op[(m * 4 + 3) * 256 + t]);
  sall[t] = v;
  if (sel == 0) cf1[m * 256 + t] = v;
  __syncthreads();
  const float* W = Wop1 + (sel ? 65536 : 0);
  const int hq = (t & 63) << 2, kg = t >> 6, k0 = kg * 64;
  float4 acc = make_float4(0.f, 0.f, 0.f, 0.f);
  #pragma unroll 4
  for (int k = k0; k < k0 + 64; ++k)
    acc = fma4(sall[k], ld4(W + k * 256 + hq), acc);
  st4(&red[kg][hq], acc);
  __syncthreads();
  if (kg == 0) {
    float4 r = add4(add4(ld4(&red[0][hq]), ld4(&red[1][hq])),
                    add4(ld4(&red[2][hq]), ld4(&red[3][hq])));
    st4(&((sel ? a2 : a1)[m * 256 + hq]), r);
  }
}

// ---------------------------------------------------------------------------
// K5: ch/sem/feats; cf2 combined inline from part_op (it1).
// ---------------------------------------------------------------------------
__global__ void __launch_bounds__(256) k_final(
    const float* __restrict__ cf0, const float* __restrict__ cf1,
    const float* __restrict__ part_op,
    const float* __restrict__ Wch, const float* __restrict__ bch,
    const float* __restrict__ Wsem, const float* __restrict__ bsem,
    const float* __restrict__ Wch2, const float* __restrict__ bch2,
    float* __restrict__ out_feats, float* __restrict__ out_sem)
{
  const int m  = blockIdx.x;
  const int t  = threadIdx.x;
  const int hq = (t & 63) << 2;
  const int kg = t >> 6;
  __shared__ float sall[768];
  __shared__ float sch[256];
  __shared__ float red[4][256];
  __shared__ float redS[4][64];

  sall[t]       = cf0[m * 256 + t];
  sall[256 + t] = cf1[m * 256 + t];
  {
    float v = part_op[(m * 4 + 0) * 256 + t];
    v = fmaxf(v, part_op[(m * 4 + 1) * 256 + t]);
    v = fmaxf(v, part_op[(m * 4 + 2) * 256 + t]);
    v = fmaxf(v, part_op[(m * 4 + 3) * 256 + t]);
    sall[512 + t] = v;
  }
  __syncthreads();

  {
    float4 acc = make_float4(0.f, 0.f, 0.f, 0.f);
    const int k0 = kg * 192;
    #pragma unroll 8
    for (int k = k0; k < k0 + 192; ++k)
      acc = fma4(sall[k], ld4(Wch + k * 256 + hq), acc);
    st4(&red[kg][hq], acc);
  }
  __syncthreads();
  if (kg == 0) {
    float4 r = add4(add4(ld4(&red[0][hq]), ld4(&red[1][hq])),
                    add4(ld4(&red[2][hq]), ld4(&red[3][hq])));
    r = relu4(add4(r, ld4(bch + hq)));
    st4(&sch[hq], r);
  }
  __syncthreads();

  {
    float4 f = make_float4(0.f, 0.f, 0.f, 0.f);
    const int k0 = kg * 64;
    #pragma unroll 8
    for (int k = k0; k < k0 + 64; ++k)
      f = fma4(sch[k], ld4(Wch2 + k * 256 + hq), f);
    const int s = t & 63;
    float sv = 0.f;
    if (s < 57) {
      #pragma unroll 8
      for (int k = k0; k < k0 + 64; ++k)
        sv = fmaf(sch[k], Wsem[k * 57 + s], sv);
    }
    redS[kg][s] = sv;
    __syncthreads();
    st4(&red[kg][hq], f);
  }
  __syncthreads();
  if (kg == 0) {
    float4 r = add4(add4(ld4(&red[0][hq]), ld4(&red[1][hq])),
                    add4(ld4(&red[2][hq]), ld4(&red[3][hq])));
    r = relu4(add4(r, ld4(bch2 + hq)));
    st4(&out_feats[m * 256 + hq], r);
    const int s = t & 63;
    if (s < 57)
      out_sem[m * 57 + s] = redS[0][s] + redS[1][s] + redS[2][s] + redS[3][s]
                          + bsem[s];
  }
}

// ---------------------------------------------------------------------------
extern "C" void kernel_launch(void* const* d_in, const int* in_sizes, int n_in,
                              void* d_out, int out_size, void* d_ws, size_t ws_size,
                              hipStream_t stream)
{
  const float* pf   = (const float*)d_in[0];
  const float* Wp   = (const float*)d_in[1];
  const float* bp   = (const float*)d_in[2];
  const float* Wex  = (const float*)d_in[3];
  const float* bex  = (const float*)d_in[4];
  const float* Wel  = (const float*)d_in[5];
  const float* bel  = (const float*)d_in[6];
  const float* Wee  = (const float*)d_in[7];
  const float* bee  = (const float*)d_in[8];
  const float* Wop  = (const float*)d_in[9];
  const float* bop  = (const float*)d_in[10];
  const float* Wch  = (const float*)d_in[11];
  const float* bch  = (const float*)d_in[12];
  const float* Wsem = (const float*)d_in[13];
  const float* bsem = (const float*)d_in[14];
  const float* Wch2 = (const float*)d_in[15];
  const float* bch2 = (const float*)d_in[16];

  // Output layout (fp32): feats | sem | exists | ee
  float* out_feats = (float*)d_out;
  float* out_sem   = out_feats + M_ * F_;
  float* out_ex    = out_sem + M_ * NSEM_;
  float* out_ee    = out_ex + M_;

  // Workspace (floats). part (2 MB, 16 chunks) overlays part_op.
  float* ws = (float*)d_ws;
  float* cf0 = ws;                     // 32768
  float* cf1 = ws + 32768;             // 32768
  float* Ab  = ws + 65536;             // 32768
  float* Bb  = ws + 98304;             // 32768
  float* a1  = ws + 131072;            // 32768
  float* a2  = ws + 163840;            // 32768
  float* part    = ws + 196608;        // 524288 (dead after stage1)
  float* part_op = ws + 196608;        // 131072 (overlay)
  unsigned short* W36F = (unsigned short*)(ws + 720896);  // 131072 bf16

  const float* Wop0 = Wop;               // iteration 0 block (772*256 floats)
  const float* Wop1 = Wop + 197632;      // iteration 1 block

  k_parent_partial<<<512, 256, 0, stream>>>(pf, Wp, part);
  k_stage1<<<256, 256, 0, stream>>>(part, bp, Wel, Wop0, Wex, bex,
                                    cf0, Ab, Bb, a1, a2, out_ex);
  k_cvt_w<<<256, 256, 0, stream>>>(Wop, W36F);

  k_gemm_epi<0><<<512, 512, 0, stream>>>(Ab, Bb, bel, W36F, Wee, bee,
                                         a1, a2, Wop0, bop, out_ex,
                                         out_ee, part_op);
  k_a12b<<<256, 256, 0, stream>>>(part_op, Wop1, cf1, a1, a2);
  k_gemm_epi<1><<<512, 512, 0, stream>>>(Ab, Bb, bel, W36F, Wee, bee,
                                         a1, a2, Wop1, bop + 256, out_ex,
                                         out_ee, part_op);
  k_final<<<128, 256, 0, stream>>>(cf0, cf1, part_op, Wch, bch, Wsem, bsem,
                                   Wch2, bch2, out_feats, out_sem);
}